// Round 10
// baseline (530.226 us; speedup 1.0000x reference)
//
#include <hip/hip_runtime.h>

#define DIM 64
#define RPB 1024              // rows per coarse bucket
#define RPB_SHIFT 10
#define NBMAX 1024            // max coarse buckets supported
#define CHUNK 4096            // edges per bin_edges block
#define EPT 16                // edges per thread in bin_edges (CHUNK/256)
#define CAPT 35               // records per thread in fused sort (cap 8960 = mean+8.6 sigma)
#define SREC_CAP (CAPT * 256) // 8960 staged records (70 KB LDS)
#define NPG4 16               // nodes per 4-lane group in fused gather (RPB/64)

typedef unsigned long long u64;
typedef unsigned int u32;
typedef unsigned short u16;
typedef float f4v __attribute__((ext_vector_type(4)));
typedef _Float16 h4 __attribute__((ext_vector_type(4)));
typedef _Float16 h8 __attribute__((ext_vector_type(8)));

// ---------------- idx width detection + counts zeroing ---------------------
__global__ void detect_idx_width(const unsigned int* __restrict__ idx_words,
                                 int* __restrict__ flag,
                                 int* __restrict__ counts) {
    __shared__ unsigned int s_or[256];
    if (counts)
        for (int i = threadIdx.x; i < NBMAX; i += 256) counts[i] = 0;
    unsigned int acc = 0;
    for (int i = threadIdx.x; i < 4096; i += blockDim.x)
        acc |= idx_words[2 * i + 1];
    s_or[threadIdx.x] = acc;
    __syncthreads();
    for (int s = 128; s > 0; s >>= 1) {
        if (threadIdx.x < s) s_or[threadIdx.x] |= s_or[threadIdx.x + s];
        __syncthreads();
    }
    if (threadIdx.x == 0) *flag = (s_or[0] == 0) ? 1 : 0;
}

__device__ __forceinline__ int load_idx(const void* ei, int use64, long long i) {
    return use64 ? (int)((const long long*)ei)[i] : ((const int*)ei)[i];
}

__device__ __forceinline__ int load_idx_nt(const void* ei, int use64, long long i) {
    return use64 ? (int)__builtin_nontemporal_load(&((const long long*)ei)[i])
                 : __builtin_nontemporal_load(&((const int*)ei)[i]);
}

// block-wide exclusive scan helper over per-thread sums (wave shuffles +
// 4-entry LDS exchange; ONE barrier inside). 256-thread blocks only.
__device__ __forceinline__ u32 quad_scan_ex(u32 qs, u32* wtot, int tid, u32* total_out) {
    u32 inc = qs;
    #pragma unroll
    for (int d = 1; d < 64; d <<= 1) {
        u32 v = __shfl_up(inc, d, 64);
        if ((tid & 63) >= d) inc += v;
    }
    if ((tid & 63) == 63) wtot[tid >> 6] = inc;
    __syncthreads();
    int w = tid >> 6;
    u32 woff = 0;
    #pragma unroll
    for (int k = 0; k < 3; ++k) woff += (k < w) ? wtot[k] : 0;
    if (total_out) *total_out = wtot[0] + wtot[1] + wtot[2] + wtot[3];
    return woff + inc - qs;
}

// ---------------- fused prep: convert role + coarse-hist role --------------
__global__ __launch_bounds__(256) void prep(const f4v* __restrict__ u4,
                                            const f4v* __restrict__ i4,
                                            long long usz4, long long tot4,
                                            h4* __restrict__ dst,
                                            const void* __restrict__ ei,
                                            const int* __restrict__ flag,
                                            int* __restrict__ counts,
                                            int num_edges,
                                            int convBlocks, int histBlocks) {
    if ((int)blockIdx.x < convBlocks) {
        long long stride = (long long)convBlocks * 256;
        for (long long idx = (long long)blockIdx.x * 256 + threadIdx.x;
             idx < tot4; idx += stride) {
            const f4v* src = (idx < usz4) ? (u4 + idx) : (i4 + (idx - usz4));
            f4v f = __builtin_nontemporal_load(src);
            h4 o;
            o.x = (_Float16)f.x; o.y = (_Float16)f.y;
            o.z = (_Float16)f.z; o.w = (_Float16)f.w;
            dst[idx] = o;      // temporal: keep table LLC-resident for gather
        }
    } else {
        __shared__ int h[NBMAX];
        for (int b = threadIdx.x; b < NBMAX; b += 256) h[b] = 0;
        __syncthreads();
        int use64 = *flag;
        int hb = (int)blockIdx.x - convBlocks;
        long long tid = (long long)hb * 256 + threadIdx.x;
        long long stride = (long long)histBlocks * 256;
        long long npairs = (long long)num_edges >> 1;
        const u64* p = (const u64*)ei;
        if (use64) {
            for (long long e = tid; e < npairs; e += stride) {
                u64 a = __builtin_nontemporal_load(&p[2 * e]);
                u64 b = __builtin_nontemporal_load(&p[2 * e + 1]);
                atomicAdd(&h[(int)(u32)a >> RPB_SHIFT], 1);
                atomicAdd(&h[(int)(u32)b >> RPB_SHIFT], 1);
            }
        } else {
            for (long long e = tid; e < npairs; e += stride) {
                u64 v = __builtin_nontemporal_load(&p[e]);
                atomicAdd(&h[(int)(u32)v >> RPB_SHIFT], 1);
                atomicAdd(&h[(int)(u32)(v >> 32) >> RPB_SHIFT], 1);
            }
        }
        if (tid == 0 && (num_edges & 1)) {
            int r = load_idx(ei, use64, num_edges - 1);
            atomicAdd(&h[r >> RPB_SHIFT], 1);
        }
        __syncthreads();
        for (int b = threadIdx.x; b < NBMAX; b += 256)
            if (h[b]) atomicAdd(&counts[b], h[b]);
    }
}

// ---------------- standalone hist (f32 fallback path) ----------------------
__global__ __launch_bounds__(256) void hist_coarse(const void* __restrict__ ei,
                                                   const int* __restrict__ flag,
                                                   int* __restrict__ counts,
                                                   int num_edges) {
    __shared__ int h[NBMAX];
    for (int b = threadIdx.x; b < NBMAX; b += 256) h[b] = 0;
    __syncthreads();
    int use64 = *flag;
    long long tid = (long long)blockIdx.x * 256 + threadIdx.x;
    long long stride = (long long)gridDim.x * 256;
    long long npairs = (long long)num_edges >> 1;
    const u64* p = (const u64*)ei;
    if (use64) {
        for (long long e = tid; e < npairs; e += stride) {
            u64 a = __builtin_nontemporal_load(&p[2 * e]);
            u64 b = __builtin_nontemporal_load(&p[2 * e + 1]);
            atomicAdd(&h[(int)(u32)a >> RPB_SHIFT], 1);
            atomicAdd(&h[(int)(u32)b >> RPB_SHIFT], 1);
        }
    } else {
        for (long long e = tid; e < npairs; e += stride) {
            u64 v = __builtin_nontemporal_load(&p[e]);
            atomicAdd(&h[(int)(u32)v >> RPB_SHIFT], 1);
            atomicAdd(&h[(int)(u32)(v >> 32) >> RPB_SHIFT], 1);
        }
    }
    if (tid == 0 && (num_edges & 1)) {
        int r = load_idx(ei, use64, num_edges - 1);
        atomicAdd(&h[r >> RPB_SHIFT], 1);
    }
    __syncthreads();
    for (int b = threadIdx.x; b < NBMAX; b += 256)
        if (h[b]) atomicAdd(&counts[b], h[b]);
}

// ---------------- scan of 1024 bucket counts (1 block) ---------------------
__global__ __launch_bounds__(256) void scan_buckets(const int* __restrict__ counts,
                                                    int* __restrict__ offs,
                                                    int* __restrict__ gcursor,
                                                    int* __restrict__ offs2, int nbkt) {
    __shared__ u32 wtot[4];
    int t = threadIdx.x;
    int4 h = ((const int4*)counts)[t];
    u32 qs = (u32)(h.x + h.y + h.z + h.w);
    u32 total;
    u32 ex = quad_scan_ex(qs, wtot, t, &total);
    int o0 = (int)ex, o1 = o0 + h.x, o2 = o1 + h.y, o3 = o2 + h.z;
    offs[4*t] = o0; offs[4*t+1] = o1; offs[4*t+2] = o2; offs[4*t+3] = o3;
    gcursor[4*t] = o0; gcursor[4*t+1] = o1; gcursor[4*t+2] = o2; gcursor[4*t+3] = o3;
    if (t == 255) {
        offs[NBMAX] = (int)total;
        if (offs2) offs2[(long long)nbkt << RPB_SHIFT] = (int)total; // f32 path
    }
}

// ---------------- pass 3: LDS-staged coarse binning (R7-proven) ------------
// record: [w:32][rowlocal:10][col:20]
__global__ __launch_bounds__(256) void bin_edges(const void* __restrict__ ei,
                                                 const float* __restrict__ vals,
                                                 const int* __restrict__ flag,
                                                 int* __restrict__ gcursor,
                                                 u64* __restrict__ recs,
                                                 int num_edges) {
    __shared__ u32 hist[NBMAX];     // counts, then running cursor
    __shared__ u32 scanL[NBMAX];
    __shared__ u32 gbase[NBMAX];
    __shared__ u32 wtot[4];
    __shared__ u64 payload[CHUNK];
    __shared__ u16 bidv[CHUNK];

    int tid = threadIdx.x;
    long long base = (long long)blockIdx.x * CHUNK;
    int n = (int)min((long long)CHUNK, (long long)num_edges - base);
    int use64 = *flag;

    for (int b = tid; b < NBMAX; b += 256) hist[b] = 0;
    __syncthreads();

    int rows_[EPT]; int cols_[EPT]; float ws_[EPT];
    #pragma unroll
    for (int i = 0; i < EPT; ++i) {
        int j = tid + i * 256;
        rows_[i] = -1;
        if (j < n) {
            long long e = base + j;
            rows_[i] = load_idx_nt(ei, use64, e);
            cols_[i] = load_idx_nt(ei, use64, (long long)num_edges + e);
            ws_[i]   = __builtin_nontemporal_load(&vals[e]);
            atomicAdd(&hist[rows_[i] >> RPB_SHIFT], 1u);
        }
    }
    __syncthreads();

    // exclusive scan of 1024 counts (wave-shuffle, 1 barrier)
    u32 h0 = hist[4*tid], h1 = hist[4*tid+1], h2 = hist[4*tid+2], h3 = hist[4*tid+3];
    u32 ex = quad_scan_ex(h0 + h1 + h2 + h3, wtot, tid, nullptr);
    scanL[4*tid]   = ex;
    scanL[4*tid+1] = ex + h0;
    scanL[4*tid+2] = ex + h0 + h1;
    scanL[4*tid+3] = ex + h0 + h1 + h2;
    __syncthreads();

    // reserve global space per bucket
    for (int b = tid; b < NBMAX; b += 256) {
        u32 c = hist[b];
        gbase[b] = c ? (u32)atomicAdd(&gcursor[b], (int)c) : 0u;
    }
    __syncthreads();
    for (int b = tid; b < NBMAX; b += 256) hist[b] = scanL[b];
    __syncthreads();

    // scatter records into LDS ordered by bucket
    #pragma unroll
    for (int i = 0; i < EPT; ++i) {
        if (rows_[i] >= 0) {
            int b = rows_[i] >> RPB_SHIFT;
            u32 pos = atomicAdd(&hist[b], 1u);
            u32 rl = (u32)(rows_[i] & (RPB - 1));
            payload[pos] = ((u64)__float_as_uint(ws_[i]) << 32) | (rl << 20) | (u32)cols_[i];
            bidv[pos] = (u16)b;
        }
    }
    __syncthreads();

    // flush: consecutive LDS slots -> consecutive global slots per bucket run
    for (int j = tid; j < n; j += 256) {
        u64 rec = payload[j];
        int b = bidv[j];
        recs[gbase[b] + (u32)j - scanL[b]] = rec;
    }
}

// ---------------- fp16: FUSED per-bucket sort + gather ---------------------
// Gather is split into two dim-phases: phase 0 reads only the first 64 B
// of each table row (dims 0-31) for ALL the block's nodes, phase 1 the
// second 64 B. Per-phase table working set = 64 MB (vs 128) -> LLC-resident
// despite stream pollution, converting ~half the table HBM re-fetches into
// L3 hits. 4-lane groups (lane l4 owns 16 B of the half-row); total line
// traffic unchanged.
#define ACC8(P0, P1, W, V) \
    P0.x += W * (float)V[0]; P0.y += W * (float)V[1]; \
    P0.z += W * (float)V[2]; P0.w += W * (float)V[3]; \
    P1.x += W * (float)V[4]; P1.y += W * (float)V[5]; \
    P1.z += W * (float)V[6]; P1.w += W * (float)V[7];

__global__ __launch_bounds__(256, 2) void sortgather_h(const int* __restrict__ offs,
                                                       const u64* __restrict__ recs,
                                                       const h8* __restrict__ hemb8,
                                                       float* __restrict__ out,
                                                       int num_nodes) {
    __shared__ u64 s_recs[SREC_CAP];     // 70 KB
    __shared__ u32 node_beg[RPB + 1];    // 4 KB
    __shared__ u32 cursor[RPB];          // 4 KB (bins, then scatter cursor)
    __shared__ u32 wtot[4];

    int b  = blockIdx.x;
    int t  = threadIdx.x;
    int beg = offs[b], end = offs[b + 1];
    int cnt = end - beg;
    int row0 = b << RPB_SHIFT;

    if (cnt <= SREC_CAP) {
        // ---- sort phase: registers -> exact LDS positions ----
        u64 r_[CAPT];
        #pragma unroll
        for (int k = 0; k < CAPT; ++k) {
            int j = t + k * 256;
            r_[k] = (j < cnt) ? __builtin_nontemporal_load(&recs[beg + j]) : 0ull;
        }
        for (int i = t; i < RPB; i += 256) cursor[i] = 0;
        __syncthreads();
        #pragma unroll
        for (int k = 0; k < CAPT; ++k) {
            int j = t + k * 256;
            if (j < cnt) atomicAdd(&cursor[(u32)(r_[k] >> 20) & (RPB - 1)], 1u);
        }
        __syncthreads();
        u32 c0[4]; u32 s = 0;
        #pragma unroll
        for (int i = 0; i < 4; ++i) { c0[i] = cursor[t * 4 + i]; s += c0[i]; }
        u32 ex = quad_scan_ex(s, wtot, t, nullptr);
        #pragma unroll
        for (int i = 0; i < 4; ++i) {
            node_beg[t * 4 + i] = ex;
            cursor[t * 4 + i] = ex;
            ex += c0[i];
        }
        if (t == 0) node_beg[RPB] = (u32)cnt;
        __syncthreads();
        #pragma unroll
        for (int k = 0; k < CAPT; ++k) {
            int j = t + k * 256;
            if (j < cnt) {
                u32 rl = (u32)(r_[k] >> 20) & (RPB - 1);
                u32 pos = atomicAdd(&cursor[rl], 1u);
                s_recs[pos] = r_[k];
            }
        }
        __syncthreads();

        // ---- gather: 4-lane group g4 owns nodes [g4*16, g4*16+16),
        //      phase-major over dim halves for table locality ----
        int l4 = t & 3;
        int g4 = t >> 2;                 // 0..63
        for (int ph = 0; ph < 2; ++ph) {
            const h8* tab = hemb8 + (ph << 2) + l4;   // half-row base, lane slot
            for (int nn = 0; nn < NPG4; ++nn) {
                int ln = g4 * NPG4 + nn;
                int node = row0 + ln;
                if (node >= num_nodes) break;
                int nb = (int)node_beg[ln];
                int ne = (int)node_beg[ln + 1];

                float4 p0 = make_float4(0.f,0.f,0.f,0.f), p1 = make_float4(0.f,0.f,0.f,0.f);
                float4 q0 = make_float4(0.f,0.f,0.f,0.f), q1 = make_float4(0.f,0.f,0.f,0.f);

                int i = nb;
                for (; i + 8 <= ne; i += 8) {
                    u64 s0 = s_recs[i];     u64 s1 = s_recs[i + 1];
                    u64 s2 = s_recs[i + 2]; u64 s3 = s_recs[i + 3];
                    u64 s4 = s_recs[i + 4]; u64 s5 = s_recs[i + 5];
                    u64 s6 = s_recs[i + 6]; u64 s7 = s_recs[i + 7];
                    h8 v0 = tab[((u32)s0 & 0xFFFFFu) << 3];
                    h8 v1 = tab[((u32)s1 & 0xFFFFFu) << 3];
                    h8 v2 = tab[((u32)s2 & 0xFFFFFu) << 3];
                    h8 v3 = tab[((u32)s3 & 0xFFFFFu) << 3];
                    h8 v4 = tab[((u32)s4 & 0xFFFFFu) << 3];
                    h8 v5 = tab[((u32)s5 & 0xFFFFFu) << 3];
                    h8 v6 = tab[((u32)s6 & 0xFFFFFu) << 3];
                    h8 v7 = tab[((u32)s7 & 0xFFFFFu) << 3];
                    float w0 = __uint_as_float((u32)(s0 >> 32));
                    float w1 = __uint_as_float((u32)(s1 >> 32));
                    float w2 = __uint_as_float((u32)(s2 >> 32));
                    float w3 = __uint_as_float((u32)(s3 >> 32));
                    float w4 = __uint_as_float((u32)(s4 >> 32));
                    float w5 = __uint_as_float((u32)(s5 >> 32));
                    float w6 = __uint_as_float((u32)(s6 >> 32));
                    float w7 = __uint_as_float((u32)(s7 >> 32));
                    ACC8(p0, p1, w0, v0); ACC8(q0, q1, w1, v1);
                    ACC8(p0, p1, w2, v2); ACC8(q0, q1, w3, v3);
                    ACC8(p0, p1, w4, v4); ACC8(q0, q1, w5, v5);
                    ACC8(p0, p1, w6, v6); ACC8(q0, q1, w7, v7);
                }
                if (i < ne) {
                    int last = ne - 1;
                    int e1 = min(i + 1, last), e2 = min(i + 2, last);
                    int e3 = min(i + 3, last), e4 = min(i + 4, last);
                    int e5 = min(i + 5, last), e6 = min(i + 6, last);
                    u64 s0 = s_recs[i];  u64 s1 = s_recs[e1];
                    u64 s2 = s_recs[e2]; u64 s3 = s_recs[e3];
                    u64 s4 = s_recs[e4]; u64 s5 = s_recs[e5];
                    u64 s6 = s_recs[e6];
                    h8 v0 = tab[((u32)s0 & 0xFFFFFu) << 3];
                    h8 v1 = tab[((u32)s1 & 0xFFFFFu) << 3];
                    h8 v2 = tab[((u32)s2 & 0xFFFFFu) << 3];
                    h8 v3 = tab[((u32)s3 & 0xFFFFFu) << 3];
                    h8 v4 = tab[((u32)s4 & 0xFFFFFu) << 3];
                    h8 v5 = tab[((u32)s5 & 0xFFFFFu) << 3];
                    h8 v6 = tab[((u32)s6 & 0xFFFFFu) << 3];
                    float w0 = __uint_as_float((u32)(s0 >> 32));
                    float w1 = (i + 1 < ne) ? __uint_as_float((u32)(s1 >> 32)) : 0.f;
                    float w2 = (i + 2 < ne) ? __uint_as_float((u32)(s2 >> 32)) : 0.f;
                    float w3 = (i + 3 < ne) ? __uint_as_float((u32)(s3 >> 32)) : 0.f;
                    float w4 = (i + 4 < ne) ? __uint_as_float((u32)(s4 >> 32)) : 0.f;
                    float w5 = (i + 5 < ne) ? __uint_as_float((u32)(s5 >> 32)) : 0.f;
                    float w6 = (i + 6 < ne) ? __uint_as_float((u32)(s6 >> 32)) : 0.f;
                    ACC8(p0, p1, w0, v0); ACC8(q0, q1, w1, v1);
                    ACC8(p0, p1, w2, v2); ACC8(q0, q1, w3, v3);
                    ACC8(p0, p1, w4, v4); ACC8(q0, q1, w5, v5);
                    ACC8(p0, p1, w6, v6);
                }

                p0.x += q0.x; p0.y += q0.y; p0.z += q0.z; p0.w += q0.w;
                p1.x += q1.x; p1.y += q1.y; p1.z += q1.z; p1.w += q1.w;
                f4v o0; o0.x = p0.x; o0.y = p0.y; o0.z = p0.z; o0.w = p0.w;
                f4v o1; o1.x = p1.x; o1.y = p1.y; o1.z = p1.z; o1.w = p1.w;
                // lane l4 owns dims [ph*32 + l4*8, +8) of node's 64-float row
                f4v* dst = (f4v*)out + ((long long)node << 4) + (ph << 3) + (l4 << 1);
                __builtin_nontemporal_store(o0, dst);
                __builtin_nontemporal_store(o1, dst + 1);
            }
        }
    } else {
        // overflow slow path (cnt > SREC_CAP): per node, scan the whole
        // coarse bucket from global with rowlocal + bound masking (8-lane
        // groups, full rows; hit with ~0 probability).
        int l8 = t & 7;
        int g8 = t >> 3;
        for (int nn = 0; nn < 32; ++nn) {
            int ln = g8 * 32 + nn;
            int node = row0 + ln;
            if (node >= num_nodes) break;
            u32 rl = (u32)ln;

            float4 p0 = make_float4(0.f,0.f,0.f,0.f), p1 = make_float4(0.f,0.f,0.f,0.f);
            float4 q0 = make_float4(0.f,0.f,0.f,0.f), q1 = make_float4(0.f,0.f,0.f,0.f);
            int last = end - 1;
            u32 rm = RPB - 1;
            for (int i = beg; i < end; i += 4) {
                int e1 = min(i + 1, last), e2 = min(i + 2, last), e3 = min(i + 3, last);
                u64 s0 = recs[i];  u64 s1 = recs[e1];
                u64 s2 = recs[e2]; u64 s3 = recs[e3];
                h8 v0 = hemb8[(((u32)s0 & 0xFFFFFu) << 3) + l8];
                h8 v1 = hemb8[(((u32)s1 & 0xFFFFFu) << 3) + l8];
                h8 v2 = hemb8[(((u32)s2 & 0xFFFFFu) << 3) + l8];
                h8 v3 = hemb8[(((u32)s3 & 0xFFFFFu) << 3) + l8];
                float w0 = ((((u32)(s0 >> 20)) & rm) == rl)
                           ? __uint_as_float((u32)(s0 >> 32)) : 0.f;
                float w1 = (((((u32)(s1 >> 20)) & rm) == rl) & (i + 1 < end))
                           ? __uint_as_float((u32)(s1 >> 32)) : 0.f;
                float w2 = (((((u32)(s2 >> 20)) & rm) == rl) & (i + 2 < end))
                           ? __uint_as_float((u32)(s2 >> 32)) : 0.f;
                float w3 = (((((u32)(s3 >> 20)) & rm) == rl) & (i + 3 < end))
                           ? __uint_as_float((u32)(s3 >> 32)) : 0.f;
                ACC8(p0, p1, w0, v0); ACC8(q0, q1, w1, v1);
                ACC8(p0, p1, w2, v2); ACC8(q0, q1, w3, v3);
            }
            p0.x += q0.x; p0.y += q0.y; p0.z += q0.z; p0.w += q0.w;
            p1.x += q1.x; p1.y += q1.y; p1.z += q1.z; p1.w += q1.w;
            f4v o0; o0.x = p0.x; o0.y = p0.y; o0.z = p0.z; o0.w = p0.w;
            f4v o1; o1.x = p1.x; o1.y = p1.y; o1.z = p1.z; o1.w = p1.w;
            f4v* dst = (f4v*)out + ((long long)node << 4) + (l8 << 1);
            __builtin_nontemporal_store(o0, dst);
            __builtin_nontemporal_store(o1, dst + 1);
        }
    }
}

// ---------------- f32 fallback path: split sort + gather -------------------
__global__ __launch_bounds__(256, 2) void sort_bucket(const int* __restrict__ offs,
                                                      u64* __restrict__ recs,
                                                      int* __restrict__ offs2) {
    __shared__ u32 bins[RPB];    // 4 KB
    __shared__ u32 wtot[4];
    int b = blockIdx.x;
    int t = threadIdx.x;
    int beg = offs[b], end = offs[b + 1];
    int cnt = end - beg;
    int row0 = b << RPB_SHIFT;

    if (cnt > CAPT * 256) {
        for (int i = t; i < RPB; i += 256) offs2[row0 + i] = -(b + 1);
        return;
    }

    u64 r_[CAPT];
    #pragma unroll
    for (int k = 0; k < CAPT; ++k) {
        int j = t + k * 256;
        r_[k] = (j < cnt) ? recs[beg + j] : 0ull;
    }
    for (int i = t; i < RPB; i += 256) bins[i] = 0;
    __syncthreads();

    #pragma unroll
    for (int k = 0; k < CAPT; ++k) {
        int j = t + k * 256;
        if (j < cnt) atomicAdd(&bins[(u32)(r_[k] >> 20) & (RPB - 1)], 1u);
    }
    __syncthreads();

    u32 c0[4]; u32 s = 0;
    #pragma unroll
    for (int i = 0; i < 4; ++i) { c0[i] = bins[t * 4 + i]; s += c0[i]; }
    u32 ex = quad_scan_ex(s, wtot, t, nullptr);
    #pragma unroll
    for (int i = 0; i < 4; ++i) {
        bins[t * 4 + i] = ex;
        offs2[row0 + t * 4 + i] = beg + (int)ex;
        ex += c0[i];
    }
    __syncthreads();

    #pragma unroll
    for (int k = 0; k < CAPT; ++k) {
        int j = t + k * 256;
        if (j < cnt) {
            u32 rl = (u32)(r_[k] >> 20) & (RPB - 1);
            u32 pos = atomicAdd(&bins[rl], 1u);
            recs[beg + pos] = r_[k];
        }
    }
}

__device__ __forceinline__ void gstep(u64 s, u32 rl,
                                      const float* __restrict__ users,
                                      const float* __restrict__ items_m,
                                      int num_users, int l16, float4& a) {
    int c = (int)(s & 0xFFFFFu);
    float w = __uint_as_float((u32)(s >> 32));
    w = (((u32)(s >> 20) & (RPB - 1)) == rl) ? w : 0.f;
    const float* p = ((c < num_users) ? users : items_m) + ((u32)c << 6);
    float4 m = reinterpret_cast<const float4*>(p)[l16];
    a.x += w * m.x; a.y += w * m.y; a.z += w * m.z; a.w += w * m.w;
}

__global__ __launch_bounds__(256) void gather_nodes(const int* __restrict__ offs,
                                                    const int* __restrict__ offs2,
                                                    const u64* __restrict__ recs,
                                                    const float* __restrict__ users,
                                                    const float* __restrict__ items_m,
                                                    float* __restrict__ out,
                                                    int num_users, int num_nodes) {
    int node = blockIdx.x * (blockDim.x >> 6) + (threadIdx.x >> 6);
    int lane = threadIdx.x & 63;
    if (node >= num_nodes) return;
    int q   = lane >> 4;
    int l16 = lane & 15;

    int beg = offs2[node];
    int end = offs2[node + 1];
    if (beg < 0) { int b = node >> RPB_SHIFT; beg = offs[b]; end = offs[b + 1]; }
    else if (end < 0) { end = offs[(node >> RPB_SHIFT) + 1]; }
    u32 rl = (u32)(node & (RPB - 1));

    float4 a0 = make_float4(0.f, 0.f, 0.f, 0.f);
    float4 a1 = make_float4(0.f, 0.f, 0.f, 0.f);

    int i = beg + q;
    for (; i + 4 < end; i += 8) {
        u64 s0 = recs[i];
        u64 s1 = recs[i + 4];
        gstep(s0, rl, users, items_m, num_users, l16, a0);
        gstep(s1, rl, users, items_m, num_users, l16, a1);
    }
    if (i < end) {
        u64 s0 = recs[i];
        gstep(s0, rl, users, items_m, num_users, l16, a0);
    }
    a0.x += a1.x; a0.y += a1.y; a0.z += a1.z; a0.w += a1.w;

    for (int msk = 16; msk <= 32; msk <<= 1) {
        a0.x += __shfl_xor(a0.x, msk, 64);
        a0.y += __shfl_xor(a0.y, msk, 64);
        a0.z += __shfl_xor(a0.z, msk, 64);
        a0.w += __shfl_xor(a0.w, msk, 64);
    }
    if (q == 0)
        reinterpret_cast<float4*>(out)[(long long)node * 16 + l16] = a0;
}

// ---------------- fallback: R1 atomic scatter ------------------------------
__global__ __launch_bounds__(256) void scatter_edges(const void* __restrict__ edge_index,
                                                     const float* __restrict__ vals,
                                                     const float* __restrict__ users,
                                                     const float* __restrict__ items,
                                                     float* __restrict__ out,
                                                     const int* __restrict__ idx64_flag,
                                                     int num_users, int num_edges) {
    long long gid = (long long)blockIdx.x * blockDim.x + threadIdx.x;
    long long e = gid >> 4;
    int lane = (int)(gid & 15);
    if (e >= num_edges) return;
    int use64 = *idx64_flag;
    int r = load_idx(edge_index, use64, e);
    int c = load_idx(edge_index, use64, (long long)num_edges + e);
    float w = vals[e];
    const float* src = (c < num_users)
        ? (users + (long long)c * DIM)
        : (items + (long long)(c - num_users) * DIM);
    float4 m = reinterpret_cast<const float4*>(src)[lane];
    float* dst = out + (long long)r * DIM + lane * 4;
    unsafeAtomicAdd(dst + 0, m.x * w);
    unsafeAtomicAdd(dst + 1, m.y * w);
    unsafeAtomicAdd(dst + 2, m.z * w);
    unsafeAtomicAdd(dst + 3, m.w * w);
}

extern "C" void kernel_launch(void* const* d_in, const int* in_sizes, int n_in,
                              void* d_out, int out_size, void* d_ws, size_t ws_size,
                              hipStream_t stream) {
    const float* users = (const float*)d_in[0];
    const float* items = (const float*)d_in[1];
    const void*  eidx  = d_in[2];
    const float* vals  = (const float*)d_in[3];
    float* out = (float*)d_out;

    int num_users = in_sizes[0] / DIM;               // 600000
    int num_items = in_sizes[1] / DIM;               // 400000
    int num_nodes = num_users + num_items;           // 1000000
    int num_edges = in_sizes[3];                     // 8000000
    int nbkt = (num_nodes + RPB - 1) >> RPB_SHIFT;   // 977

    // workspace layout: base | offs2 (f32 path only) | hemb (f16 path)
    size_t off = 0;
    auto alloc = [&](size_t bytes) { size_t p = off; off = (off + bytes + 255) & ~(size_t)255; return p; };
    size_t o_flag   = alloc(4);
    size_t o_counts = alloc((size_t)NBMAX * 4);
    size_t o_offs   = alloc(((size_t)NBMAX + 1) * 4);
    size_t o_gcur   = alloc((size_t)NBMAX * 4);
    size_t o_recs   = alloc((size_t)num_edges * 8 + 64);   // +64: slow-path over-read pad
    size_t o_offs2  = alloc((((size_t)nbkt << RPB_SHIFT) + 1) * 4);
    size_t need_base = off;                                 // base incl. offs2
    size_t o_hemb   = alloc((size_t)num_nodes * DIM * 2);   // fp16 table, 128 MB
    size_t need_f16 = off;

    char* ws = (char*)d_ws;
    int* flag = (int*)(ws + o_flag);

    if (ws_size < need_base || nbkt > NBMAX || num_nodes > (1 << 20)) {
        detect_idx_width<<<1, 256, 0, stream>>>((const unsigned int*)eidx, flag, nullptr);
        hipMemsetAsync(d_out, 0, (size_t)out_size * sizeof(float), stream);
        long long total_threads = (long long)num_edges * 16;
        long long grid = (total_threads + 255) / 256;
        scatter_edges<<<(int)grid, 256, 0, stream>>>(
            eidx, vals, users, items, out, flag, num_users, num_edges);
        return;
    }

    int* counts  = (int*)(ws + o_counts);
    int* offs    = (int*)(ws + o_offs);
    int* gcursor = (int*)(ws + o_gcur);
    u64* recs    = (u64*)(ws + o_recs);
    int* offs2   = (int*)(ws + o_offs2);
    h4*  hemb4   = (h4*)(ws + o_hemb);

    bool use_f16 = (ws_size >= need_f16) && ((DIM % 8) == 0);

    detect_idx_width<<<1, 256, 0, stream>>>((const unsigned int*)eidx, flag, counts);

    long long usz4 = (long long)num_users * DIM / 4;
    long long tot4 = (long long)num_nodes * DIM / 4;

    if (use_f16) {
        // fused convert + hist: one dispatch, two grid roles
        const int convB = 2048, histB = 768;
        prep<<<convB + histB, 256, 0, stream>>>((const f4v*)users, (const f4v*)items,
                                                usz4, tot4, hemb4,
                                                eidx, flag, counts, num_edges,
                                                convB, histB);
    } else {
        hist_coarse<<<768, 256, 0, stream>>>(eidx, flag, counts, num_edges);
    }

    scan_buckets<<<1, 256, 0, stream>>>(counts, offs, gcursor,
                                        use_f16 ? nullptr : offs2, nbkt);

    int bin_grid = (num_edges + CHUNK - 1) / CHUNK;
    bin_edges<<<bin_grid, 256, 0, stream>>>(eidx, vals, flag, gcursor, recs, num_edges);

    if (use_f16) {
        sortgather_h<<<nbkt, 256, 0, stream>>>(offs, recs, (const h8*)hemb4,
                                               out, num_nodes);
    } else {
        sort_bucket<<<nbkt, 256, 0, stream>>>(offs, recs, offs2);
        int gg = (num_nodes + 3) / 4;
        const float* items_m = items - (size_t)num_users * DIM;
        gather_nodes<<<gg, 256, 0, stream>>>(offs, offs2, recs, users, items_m, out,
                                             num_users, num_nodes);
    }
}

// Round 11
// 518.777 us; speedup vs baseline: 1.0221x; 1.0221x over previous
//
#include <hip/hip_runtime.h>

#define DIM 64
#define RPB 1024              // rows per coarse bucket
#define RPB_SHIFT 10
#define NBMAX 1024            // max coarse buckets supported
#define CHUNK 4096            // edges per bin_edges block
#define EPT 16                // edges per thread in bin_edges (CHUNK/256)
#define CAPT 35               // records per thread in fused sort (cap 8960 = mean+8.6 sigma)
#define SREC_CAP (CAPT * 256) // 8960 staged records (70 KB LDS)
#define NPG4 16               // nodes per 4-lane group in fused gather (RPB/64)

typedef unsigned long long u64;
typedef unsigned int u32;
typedef unsigned short u16;
typedef float f4v __attribute__((ext_vector_type(4)));
typedef _Float16 h4 __attribute__((ext_vector_type(4)));
typedef _Float16 h8 __attribute__((ext_vector_type(8)));

// ---------------- idx width detection + counts zeroing ---------------------
__global__ void detect_idx_width(const unsigned int* __restrict__ idx_words,
                                 int* __restrict__ flag,
                                 int* __restrict__ counts) {
    __shared__ unsigned int s_or[256];
    if (counts)
        for (int i = threadIdx.x; i < NBMAX; i += 256) counts[i] = 0;
    unsigned int acc = 0;
    for (int i = threadIdx.x; i < 4096; i += blockDim.x)
        acc |= idx_words[2 * i + 1];
    s_or[threadIdx.x] = acc;
    __syncthreads();
    for (int s = 128; s > 0; s >>= 1) {
        if (threadIdx.x < s) s_or[threadIdx.x] |= s_or[threadIdx.x + s];
        __syncthreads();
    }
    if (threadIdx.x == 0) *flag = (s_or[0] == 0) ? 1 : 0;
}

__device__ __forceinline__ int load_idx(const void* ei, int use64, long long i) {
    return use64 ? (int)((const long long*)ei)[i] : ((const int*)ei)[i];
}

__device__ __forceinline__ int load_idx_nt(const void* ei, int use64, long long i) {
    return use64 ? (int)__builtin_nontemporal_load(&((const long long*)ei)[i])
                 : __builtin_nontemporal_load(&((const int*)ei)[i]);
}

// block-wide exclusive scan helper over per-thread sums (wave shuffles +
// 4-entry LDS exchange; ONE barrier inside). 256-thread blocks only.
__device__ __forceinline__ u32 quad_scan_ex(u32 qs, u32* wtot, int tid, u32* total_out) {
    u32 inc = qs;
    #pragma unroll
    for (int d = 1; d < 64; d <<= 1) {
        u32 v = __shfl_up(inc, d, 64);
        if ((tid & 63) >= d) inc += v;
    }
    if ((tid & 63) == 63) wtot[tid >> 6] = inc;
    __syncthreads();
    int w = tid >> 6;
    u32 woff = 0;
    #pragma unroll
    for (int k = 0; k < 3; ++k) woff += (k < w) ? wtot[k] : 0;
    if (total_out) *total_out = wtot[0] + wtot[1] + wtot[2] + wtot[3];
    return woff + inc - qs;
}

// ---------------- fused prep: convert role + coarse-hist role --------------
// Table is written as TWO split half-dim arrays: hA = dims 0-31 of every
// node (64 B/row), hB = dims 32-63. Each gather phase then touches a dense
// 64 MB array -> LLC-resident working set with no dead half-line fetches
// (R10's interleaved split re-fetched each 128 B line twice).
__global__ __launch_bounds__(256) void prep(const f4v* __restrict__ u4,
                                            const f4v* __restrict__ i4,
                                            long long usz4, long long tot4,
                                            h4* __restrict__ dstA,
                                            h4* __restrict__ dstB,
                                            const void* __restrict__ ei,
                                            const int* __restrict__ flag,
                                            int* __restrict__ counts,
                                            int num_edges,
                                            int convBlocks, int histBlocks) {
    if ((int)blockIdx.x < convBlocks) {
        long long stride = (long long)convBlocks * 256;
        for (long long idx = (long long)blockIdx.x * 256 + threadIdx.x;
             idx < tot4; idx += stride) {
            const f4v* src = (idx < usz4) ? (u4 + idx) : (i4 + (idx - usz4));
            f4v f = __builtin_nontemporal_load(src);
            h4 o;
            o.x = (_Float16)f.x; o.y = (_Float16)f.y;
            o.z = (_Float16)f.z; o.w = (_Float16)f.w;
            long long row = idx >> 4;
            int q = (int)(idx & 15);
            if (q < 8) dstA[(row << 3) + q] = o;
            else       dstB[(row << 3) + (q - 8)] = o;
        }
    } else {
        __shared__ int h[NBMAX];
        for (int b = threadIdx.x; b < NBMAX; b += 256) h[b] = 0;
        __syncthreads();
        int use64 = *flag;
        int hb = (int)blockIdx.x - convBlocks;
        long long tid = (long long)hb * 256 + threadIdx.x;
        long long stride = (long long)histBlocks * 256;
        long long npairs = (long long)num_edges >> 1;
        const u64* p = (const u64*)ei;
        if (use64) {
            for (long long e = tid; e < npairs; e += stride) {
                u64 a = __builtin_nontemporal_load(&p[2 * e]);
                u64 b = __builtin_nontemporal_load(&p[2 * e + 1]);
                atomicAdd(&h[(int)(u32)a >> RPB_SHIFT], 1);
                atomicAdd(&h[(int)(u32)b >> RPB_SHIFT], 1);
            }
        } else {
            for (long long e = tid; e < npairs; e += stride) {
                u64 v = __builtin_nontemporal_load(&p[e]);
                atomicAdd(&h[(int)(u32)v >> RPB_SHIFT], 1);
                atomicAdd(&h[(int)(u32)(v >> 32) >> RPB_SHIFT], 1);
            }
        }
        if (tid == 0 && (num_edges & 1)) {
            int r = load_idx(ei, use64, num_edges - 1);
            atomicAdd(&h[r >> RPB_SHIFT], 1);
        }
        __syncthreads();
        for (int b = threadIdx.x; b < NBMAX; b += 256)
            if (h[b]) atomicAdd(&counts[b], h[b]);
    }
}

// ---------------- standalone hist (f32 fallback path) ----------------------
__global__ __launch_bounds__(256) void hist_coarse(const void* __restrict__ ei,
                                                   const int* __restrict__ flag,
                                                   int* __restrict__ counts,
                                                   int num_edges) {
    __shared__ int h[NBMAX];
    for (int b = threadIdx.x; b < NBMAX; b += 256) h[b] = 0;
    __syncthreads();
    int use64 = *flag;
    long long tid = (long long)blockIdx.x * 256 + threadIdx.x;
    long long stride = (long long)gridDim.x * 256;
    long long npairs = (long long)num_edges >> 1;
    const u64* p = (const u64*)ei;
    if (use64) {
        for (long long e = tid; e < npairs; e += stride) {
            u64 a = __builtin_nontemporal_load(&p[2 * e]);
            u64 b = __builtin_nontemporal_load(&p[2 * e + 1]);
            atomicAdd(&h[(int)(u32)a >> RPB_SHIFT], 1);
            atomicAdd(&h[(int)(u32)b >> RPB_SHIFT], 1);
        }
    } else {
        for (long long e = tid; e < npairs; e += stride) {
            u64 v = __builtin_nontemporal_load(&p[e]);
            atomicAdd(&h[(int)(u32)v >> RPB_SHIFT], 1);
            atomicAdd(&h[(int)(u32)(v >> 32) >> RPB_SHIFT], 1);
        }
    }
    if (tid == 0 && (num_edges & 1)) {
        int r = load_idx(ei, use64, num_edges - 1);
        atomicAdd(&h[r >> RPB_SHIFT], 1);
    }
    __syncthreads();
    for (int b = threadIdx.x; b < NBMAX; b += 256)
        if (h[b]) atomicAdd(&counts[b], h[b]);
}

// ---------------- scan of 1024 bucket counts (1 block) ---------------------
__global__ __launch_bounds__(256) void scan_buckets(const int* __restrict__ counts,
                                                    int* __restrict__ offs,
                                                    int* __restrict__ gcursor,
                                                    int* __restrict__ offs2, int nbkt) {
    __shared__ u32 wtot[4];
    int t = threadIdx.x;
    int4 h = ((const int4*)counts)[t];
    u32 qs = (u32)(h.x + h.y + h.z + h.w);
    u32 total;
    u32 ex = quad_scan_ex(qs, wtot, t, &total);
    int o0 = (int)ex, o1 = o0 + h.x, o2 = o1 + h.y, o3 = o2 + h.z;
    offs[4*t] = o0; offs[4*t+1] = o1; offs[4*t+2] = o2; offs[4*t+3] = o3;
    gcursor[4*t] = o0; gcursor[4*t+1] = o1; gcursor[4*t+2] = o2; gcursor[4*t+3] = o3;
    if (t == 255) {
        offs[NBMAX] = (int)total;
        if (offs2) offs2[(long long)nbkt << RPB_SHIFT] = (int)total; // f32 path
    }
}

// ---------------- pass 3: LDS-staged coarse binning (R7-proven) ------------
// record: [w:32][rowlocal:10][col:20]
__global__ __launch_bounds__(256) void bin_edges(const void* __restrict__ ei,
                                                 const float* __restrict__ vals,
                                                 const int* __restrict__ flag,
                                                 int* __restrict__ gcursor,
                                                 u64* __restrict__ recs,
                                                 int num_edges) {
    __shared__ u32 hist[NBMAX];     // counts, then running cursor
    __shared__ u32 scanL[NBMAX];
    __shared__ u32 gbase[NBMAX];
    __shared__ u32 wtot[4];
    __shared__ u64 payload[CHUNK];
    __shared__ u16 bidv[CHUNK];

    int tid = threadIdx.x;
    long long base = (long long)blockIdx.x * CHUNK;
    int n = (int)min((long long)CHUNK, (long long)num_edges - base);
    int use64 = *flag;

    for (int b = tid; b < NBMAX; b += 256) hist[b] = 0;
    __syncthreads();

    int rows_[EPT]; int cols_[EPT]; float ws_[EPT];
    #pragma unroll
    for (int i = 0; i < EPT; ++i) {
        int j = tid + i * 256;
        rows_[i] = -1;
        if (j < n) {
            long long e = base + j;
            rows_[i] = load_idx_nt(ei, use64, e);
            cols_[i] = load_idx_nt(ei, use64, (long long)num_edges + e);
            ws_[i]   = __builtin_nontemporal_load(&vals[e]);
            atomicAdd(&hist[rows_[i] >> RPB_SHIFT], 1u);
        }
    }
    __syncthreads();

    // exclusive scan of 1024 counts (wave-shuffle, 1 barrier)
    u32 h0 = hist[4*tid], h1 = hist[4*tid+1], h2 = hist[4*tid+2], h3 = hist[4*tid+3];
    u32 ex = quad_scan_ex(h0 + h1 + h2 + h3, wtot, tid, nullptr);
    scanL[4*tid]   = ex;
    scanL[4*tid+1] = ex + h0;
    scanL[4*tid+2] = ex + h0 + h1;
    scanL[4*tid+3] = ex + h0 + h1 + h2;
    __syncthreads();

    // reserve global space per bucket
    for (int b = tid; b < NBMAX; b += 256) {
        u32 c = hist[b];
        gbase[b] = c ? (u32)atomicAdd(&gcursor[b], (int)c) : 0u;
    }
    __syncthreads();
    for (int b = tid; b < NBMAX; b += 256) hist[b] = scanL[b];
    __syncthreads();

    // scatter records into LDS ordered by bucket
    #pragma unroll
    for (int i = 0; i < EPT; ++i) {
        if (rows_[i] >= 0) {
            int b = rows_[i] >> RPB_SHIFT;
            u32 pos = atomicAdd(&hist[b], 1u);
            u32 rl = (u32)(rows_[i] & (RPB - 1));
            payload[pos] = ((u64)__float_as_uint(ws_[i]) << 32) | (rl << 20) | (u32)cols_[i];
            bidv[pos] = (u16)b;
        }
    }
    __syncthreads();

    // flush: consecutive LDS slots -> consecutive global slots per bucket run
    for (int j = tid; j < n; j += 256) {
        u64 rec = payload[j];
        int b = bidv[j];
        recs[gbase[b] + (u32)j - scanL[b]] = rec;
    }
}

// ---------------- fp16: FUSED per-bucket sort + gather ---------------------
// Gather runs two dim-phases over SPLIT half-tables (hA: dims 0-31, hB:
// dims 32-63, 64 MB each). Per-phase working set is a dense 64 MB array
// -> LLC-resident; every fetched 128 B line is fully useful (2 half-rows).
#define ACC8(P0, P1, W, V) \
    P0.x += W * (float)V[0]; P0.y += W * (float)V[1]; \
    P0.z += W * (float)V[2]; P0.w += W * (float)V[3]; \
    P1.x += W * (float)V[4]; P1.y += W * (float)V[5]; \
    P1.z += W * (float)V[6]; P1.w += W * (float)V[7];

__global__ __launch_bounds__(256, 2) void sortgather_h(const int* __restrict__ offs,
                                                       const u64* __restrict__ recs,
                                                       const h8* __restrict__ hA8,
                                                       const h8* __restrict__ hB8,
                                                       float* __restrict__ out,
                                                       int num_nodes) {
    __shared__ u64 s_recs[SREC_CAP];     // 70 KB
    __shared__ u32 node_beg[RPB + 1];    // 4 KB
    __shared__ u32 cursor[RPB];          // 4 KB (bins, then scatter cursor)
    __shared__ u32 wtot[4];

    int b  = blockIdx.x;
    int t  = threadIdx.x;
    int beg = offs[b], end = offs[b + 1];
    int cnt = end - beg;
    int row0 = b << RPB_SHIFT;

    if (cnt <= SREC_CAP) {
        // ---- sort phase: registers -> exact LDS positions ----
        u64 r_[CAPT];
        #pragma unroll
        for (int k = 0; k < CAPT; ++k) {
            int j = t + k * 256;
            r_[k] = (j < cnt) ? __builtin_nontemporal_load(&recs[beg + j]) : 0ull;
        }
        for (int i = t; i < RPB; i += 256) cursor[i] = 0;
        __syncthreads();
        #pragma unroll
        for (int k = 0; k < CAPT; ++k) {
            int j = t + k * 256;
            if (j < cnt) atomicAdd(&cursor[(u32)(r_[k] >> 20) & (RPB - 1)], 1u);
        }
        __syncthreads();
        u32 c0[4]; u32 s = 0;
        #pragma unroll
        for (int i = 0; i < 4; ++i) { c0[i] = cursor[t * 4 + i]; s += c0[i]; }
        u32 ex = quad_scan_ex(s, wtot, t, nullptr);
        #pragma unroll
        for (int i = 0; i < 4; ++i) {
            node_beg[t * 4 + i] = ex;
            cursor[t * 4 + i] = ex;
            ex += c0[i];
        }
        if (t == 0) node_beg[RPB] = (u32)cnt;
        __syncthreads();
        #pragma unroll
        for (int k = 0; k < CAPT; ++k) {
            int j = t + k * 256;
            if (j < cnt) {
                u32 rl = (u32)(r_[k] >> 20) & (RPB - 1);
                u32 pos = atomicAdd(&cursor[rl], 1u);
                s_recs[pos] = r_[k];
            }
        }
        __syncthreads();

        // ---- gather: 4-lane group g4 owns nodes [g4*16, g4*16+16),
        //      phase-major over split half-tables for LLC residency ----
        int l4 = t & 3;
        int g4 = t >> 2;                 // 0..63
        for (int ph = 0; ph < 2; ++ph) {
            const h8* tab = (ph ? hB8 : hA8) + l4;   // lane slot within 64B row
            for (int nn = 0; nn < NPG4; ++nn) {
                int ln = g4 * NPG4 + nn;
                int node = row0 + ln;
                if (node >= num_nodes) break;
                int nb = (int)node_beg[ln];
                int ne = (int)node_beg[ln + 1];

                float4 p0 = make_float4(0.f,0.f,0.f,0.f), p1 = make_float4(0.f,0.f,0.f,0.f);
                float4 q0 = make_float4(0.f,0.f,0.f,0.f), q1 = make_float4(0.f,0.f,0.f,0.f);

                int i = nb;
                for (; i + 8 <= ne; i += 8) {
                    u64 s0 = s_recs[i];     u64 s1 = s_recs[i + 1];
                    u64 s2 = s_recs[i + 2]; u64 s3 = s_recs[i + 3];
                    u64 s4 = s_recs[i + 4]; u64 s5 = s_recs[i + 5];
                    u64 s6 = s_recs[i + 6]; u64 s7 = s_recs[i + 7];
                    h8 v0 = tab[((u32)s0 & 0xFFFFFu) << 2];
                    h8 v1 = tab[((u32)s1 & 0xFFFFFu) << 2];
                    h8 v2 = tab[((u32)s2 & 0xFFFFFu) << 2];
                    h8 v3 = tab[((u32)s3 & 0xFFFFFu) << 2];
                    h8 v4 = tab[((u32)s4 & 0xFFFFFu) << 2];
                    h8 v5 = tab[((u32)s5 & 0xFFFFFu) << 2];
                    h8 v6 = tab[((u32)s6 & 0xFFFFFu) << 2];
                    h8 v7 = tab[((u32)s7 & 0xFFFFFu) << 2];
                    float w0 = __uint_as_float((u32)(s0 >> 32));
                    float w1 = __uint_as_float((u32)(s1 >> 32));
                    float w2 = __uint_as_float((u32)(s2 >> 32));
                    float w3 = __uint_as_float((u32)(s3 >> 32));
                    float w4 = __uint_as_float((u32)(s4 >> 32));
                    float w5 = __uint_as_float((u32)(s5 >> 32));
                    float w6 = __uint_as_float((u32)(s6 >> 32));
                    float w7 = __uint_as_float((u32)(s7 >> 32));
                    ACC8(p0, p1, w0, v0); ACC8(q0, q1, w1, v1);
                    ACC8(p0, p1, w2, v2); ACC8(q0, q1, w3, v3);
                    ACC8(p0, p1, w4, v4); ACC8(q0, q1, w5, v5);
                    ACC8(p0, p1, w6, v6); ACC8(q0, q1, w7, v7);
                }
                if (i < ne) {
                    int last = ne - 1;
                    int e1 = min(i + 1, last), e2 = min(i + 2, last);
                    int e3 = min(i + 3, last), e4 = min(i + 4, last);
                    int e5 = min(i + 5, last), e6 = min(i + 6, last);
                    u64 s0 = s_recs[i];  u64 s1 = s_recs[e1];
                    u64 s2 = s_recs[e2]; u64 s3 = s_recs[e3];
                    u64 s4 = s_recs[e4]; u64 s5 = s_recs[e5];
                    u64 s6 = s_recs[e6];
                    h8 v0 = tab[((u32)s0 & 0xFFFFFu) << 2];
                    h8 v1 = tab[((u32)s1 & 0xFFFFFu) << 2];
                    h8 v2 = tab[((u32)s2 & 0xFFFFFu) << 2];
                    h8 v3 = tab[((u32)s3 & 0xFFFFFu) << 2];
                    h8 v4 = tab[((u32)s4 & 0xFFFFFu) << 2];
                    h8 v5 = tab[((u32)s5 & 0xFFFFFu) << 2];
                    h8 v6 = tab[((u32)s6 & 0xFFFFFu) << 2];
                    float w0 = __uint_as_float((u32)(s0 >> 32));
                    float w1 = (i + 1 < ne) ? __uint_as_float((u32)(s1 >> 32)) : 0.f;
                    float w2 = (i + 2 < ne) ? __uint_as_float((u32)(s2 >> 32)) : 0.f;
                    float w3 = (i + 3 < ne) ? __uint_as_float((u32)(s3 >> 32)) : 0.f;
                    float w4 = (i + 4 < ne) ? __uint_as_float((u32)(s4 >> 32)) : 0.f;
                    float w5 = (i + 5 < ne) ? __uint_as_float((u32)(s5 >> 32)) : 0.f;
                    float w6 = (i + 6 < ne) ? __uint_as_float((u32)(s6 >> 32)) : 0.f;
                    ACC8(p0, p1, w0, v0); ACC8(q0, q1, w1, v1);
                    ACC8(p0, p1, w2, v2); ACC8(q0, q1, w3, v3);
                    ACC8(p0, p1, w4, v4); ACC8(q0, q1, w5, v5);
                    ACC8(p0, p1, w6, v6);
                }

                p0.x += q0.x; p0.y += q0.y; p0.z += q0.z; p0.w += q0.w;
                p1.x += q1.x; p1.y += q1.y; p1.z += q1.z; p1.w += q1.w;
                f4v o0; o0.x = p0.x; o0.y = p0.y; o0.z = p0.z; o0.w = p0.w;
                f4v o1; o1.x = p1.x; o1.y = p1.y; o1.z = p1.z; o1.w = p1.w;
                // lane l4 owns dims [ph*32 + l4*8, +8) of node's 64-float row
                f4v* dst = (f4v*)out + ((long long)node << 4) + (ph << 3) + (l4 << 1);
                __builtin_nontemporal_store(o0, dst);
                __builtin_nontemporal_store(o1, dst + 1);
            }
        }
    } else {
        // overflow slow path (cnt > SREC_CAP): per node, scan the whole
        // coarse bucket from global with rowlocal + bound masking (8-lane
        // groups; lanes 0-3 read hA, lanes 4-7 read hB; ~0 probability).
        int l8 = t & 7;
        int g8 = t >> 3;
        const h8* tab = (l8 < 4) ? (hA8 + l8) : (hB8 + (l8 - 4));
        for (int nn = 0; nn < 32; ++nn) {
            int ln = g8 * 32 + nn;
            int node = row0 + ln;
            if (node >= num_nodes) break;
            u32 rl = (u32)ln;

            float4 p0 = make_float4(0.f,0.f,0.f,0.f), p1 = make_float4(0.f,0.f,0.f,0.f);
            float4 q0 = make_float4(0.f,0.f,0.f,0.f), q1 = make_float4(0.f,0.f,0.f,0.f);
            int last = end - 1;
            u32 rm = RPB - 1;
            for (int i = beg; i < end; i += 4) {
                int e1 = min(i + 1, last), e2 = min(i + 2, last), e3 = min(i + 3, last);
                u64 s0 = recs[i];  u64 s1 = recs[e1];
                u64 s2 = recs[e2]; u64 s3 = recs[e3];
                h8 v0 = tab[((u32)s0 & 0xFFFFFu) << 2];
                h8 v1 = tab[((u32)s1 & 0xFFFFFu) << 2];
                h8 v2 = tab[((u32)s2 & 0xFFFFFu) << 2];
                h8 v3 = tab[((u32)s3 & 0xFFFFFu) << 2];
                float w0 = ((((u32)(s0 >> 20)) & rm) == rl)
                           ? __uint_as_float((u32)(s0 >> 32)) : 0.f;
                float w1 = (((((u32)(s1 >> 20)) & rm) == rl) & (i + 1 < end))
                           ? __uint_as_float((u32)(s1 >> 32)) : 0.f;
                float w2 = (((((u32)(s2 >> 20)) & rm) == rl) & (i + 2 < end))
                           ? __uint_as_float((u32)(s2 >> 32)) : 0.f;
                float w3 = (((((u32)(s3 >> 20)) & rm) == rl) & (i + 3 < end))
                           ? __uint_as_float((u32)(s3 >> 32)) : 0.f;
                ACC8(p0, p1, w0, v0); ACC8(q0, q1, w1, v1);
                ACC8(p0, p1, w2, v2); ACC8(q0, q1, w3, v3);
            }
            p0.x += q0.x; p0.y += q0.y; p0.z += q0.z; p0.w += q0.w;
            p1.x += q1.x; p1.y += q1.y; p1.z += q1.z; p1.w += q1.w;
            f4v o0; o0.x = p0.x; o0.y = p0.y; o0.z = p0.z; o0.w = p0.w;
            f4v o1; o1.x = p1.x; o1.y = p1.y; o1.z = p1.z; o1.w = p1.w;
            // lanes 0-3 own dims [l8*8, +8); lanes 4-7 own dims [32+(l8-4)*8, +8)
            f4v* dst = (f4v*)out + ((long long)node << 4) + (l8 << 1);
            __builtin_nontemporal_store(o0, dst);
            __builtin_nontemporal_store(o1, dst + 1);
        }
    }
}

// ---------------- f32 fallback path: split sort + gather -------------------
__global__ __launch_bounds__(256, 2) void sort_bucket(const int* __restrict__ offs,
                                                      u64* __restrict__ recs,
                                                      int* __restrict__ offs2) {
    __shared__ u32 bins[RPB];    // 4 KB
    __shared__ u32 wtot[4];
    int b = blockIdx.x;
    int t = threadIdx.x;
    int beg = offs[b], end = offs[b + 1];
    int cnt = end - beg;
    int row0 = b << RPB_SHIFT;

    if (cnt > CAPT * 256) {
        for (int i = t; i < RPB; i += 256) offs2[row0 + i] = -(b + 1);
        return;
    }

    u64 r_[CAPT];
    #pragma unroll
    for (int k = 0; k < CAPT; ++k) {
        int j = t + k * 256;
        r_[k] = (j < cnt) ? recs[beg + j] : 0ull;
    }
    for (int i = t; i < RPB; i += 256) bins[i] = 0;
    __syncthreads();

    #pragma unroll
    for (int k = 0; k < CAPT; ++k) {
        int j = t + k * 256;
        if (j < cnt) atomicAdd(&bins[(u32)(r_[k] >> 20) & (RPB - 1)], 1u);
    }
    __syncthreads();

    u32 c0[4]; u32 s = 0;
    #pragma unroll
    for (int i = 0; i < 4; ++i) { c0[i] = bins[t * 4 + i]; s += c0[i]; }
    u32 ex = quad_scan_ex(s, wtot, t, nullptr);
    #pragma unroll
    for (int i = 0; i < 4; ++i) {
        bins[t * 4 + i] = ex;
        offs2[row0 + t * 4 + i] = beg + (int)ex;
        ex += c0[i];
    }
    __syncthreads();

    #pragma unroll
    for (int k = 0; k < CAPT; ++k) {
        int j = t + k * 256;
        if (j < cnt) {
            u32 rl = (u32)(r_[k] >> 20) & (RPB - 1);
            u32 pos = atomicAdd(&bins[rl], 1u);
            recs[beg + pos] = r_[k];
        }
    }
}

__device__ __forceinline__ void gstep(u64 s, u32 rl,
                                      const float* __restrict__ users,
                                      const float* __restrict__ items_m,
                                      int num_users, int l16, float4& a) {
    int c = (int)(s & 0xFFFFFu);
    float w = __uint_as_float((u32)(s >> 32));
    w = (((u32)(s >> 20) & (RPB - 1)) == rl) ? w : 0.f;
    const float* p = ((c < num_users) ? users : items_m) + ((u32)c << 6);
    float4 m = reinterpret_cast<const float4*>(p)[l16];
    a.x += w * m.x; a.y += w * m.y; a.z += w * m.z; a.w += w * m.w;
}

__global__ __launch_bounds__(256) void gather_nodes(const int* __restrict__ offs,
                                                    const int* __restrict__ offs2,
                                                    const u64* __restrict__ recs,
                                                    const float* __restrict__ users,
                                                    const float* __restrict__ items_m,
                                                    float* __restrict__ out,
                                                    int num_users, int num_nodes) {
    int node = blockIdx.x * (blockDim.x >> 6) + (threadIdx.x >> 6);
    int lane = threadIdx.x & 63;
    if (node >= num_nodes) return;
    int q   = lane >> 4;
    int l16 = lane & 15;

    int beg = offs2[node];
    int end = offs2[node + 1];
    if (beg < 0) { int b = node >> RPB_SHIFT; beg = offs[b]; end = offs[b + 1]; }
    else if (end < 0) { end = offs[(node >> RPB_SHIFT) + 1]; }
    u32 rl = (u32)(node & (RPB - 1));

    float4 a0 = make_float4(0.f, 0.f, 0.f, 0.f);
    float4 a1 = make_float4(0.f, 0.f, 0.f, 0.f);

    int i = beg + q;
    for (; i + 4 < end; i += 8) {
        u64 s0 = recs[i];
        u64 s1 = recs[i + 4];
        gstep(s0, rl, users, items_m, num_users, l16, a0);
        gstep(s1, rl, users, items_m, num_users, l16, a1);
    }
    if (i < end) {
        u64 s0 = recs[i];
        gstep(s0, rl, users, items_m, num_users, l16, a0);
    }
    a0.x += a1.x; a0.y += a1.y; a0.z += a1.z; a0.w += a1.w;

    for (int msk = 16; msk <= 32; msk <<= 1) {
        a0.x += __shfl_xor(a0.x, msk, 64);
        a0.y += __shfl_xor(a0.y, msk, 64);
        a0.z += __shfl_xor(a0.z, msk, 64);
        a0.w += __shfl_xor(a0.w, msk, 64);
    }
    if (q == 0)
        reinterpret_cast<float4*>(out)[(long long)node * 16 + l16] = a0;
}

// ---------------- fallback: R1 atomic scatter ------------------------------
__global__ __launch_bounds__(256) void scatter_edges(const void* __restrict__ edge_index,
                                                     const float* __restrict__ vals,
                                                     const float* __restrict__ users,
                                                     const float* __restrict__ items,
                                                     float* __restrict__ out,
                                                     const int* __restrict__ idx64_flag,
                                                     int num_users, int num_edges) {
    long long gid = (long long)blockIdx.x * blockDim.x + threadIdx.x;
    long long e = gid >> 4;
    int lane = (int)(gid & 15);
    if (e >= num_edges) return;
    int use64 = *idx64_flag;
    int r = load_idx(edge_index, use64, e);
    int c = load_idx(edge_index, use64, (long long)num_edges + e);
    float w = vals[e];
    const float* src = (c < num_users)
        ? (users + (long long)c * DIM)
        : (items + (long long)(c - num_users) * DIM);
    float4 m = reinterpret_cast<const float4*>(src)[lane];
    float* dst = out + (long long)r * DIM + lane * 4;
    unsafeAtomicAdd(dst + 0, m.x * w);
    unsafeAtomicAdd(dst + 1, m.y * w);
    unsafeAtomicAdd(dst + 2, m.z * w);
    unsafeAtomicAdd(dst + 3, m.w * w);
}

extern "C" void kernel_launch(void* const* d_in, const int* in_sizes, int n_in,
                              void* d_out, int out_size, void* d_ws, size_t ws_size,
                              hipStream_t stream) {
    const float* users = (const float*)d_in[0];
    const float* items = (const float*)d_in[1];
    const void*  eidx  = d_in[2];
    const float* vals  = (const float*)d_in[3];
    float* out = (float*)d_out;

    int num_users = in_sizes[0] / DIM;               // 600000
    int num_items = in_sizes[1] / DIM;               // 400000
    int num_nodes = num_users + num_items;           // 1000000
    int num_edges = in_sizes[3];                     // 8000000
    int nbkt = (num_nodes + RPB - 1) >> RPB_SHIFT;   // 977

    // workspace layout: base | offs2 (f32 path only) | hA,hB (f16 path)
    size_t off = 0;
    auto alloc = [&](size_t bytes) { size_t p = off; off = (off + bytes + 255) & ~(size_t)255; return p; };
    size_t o_flag   = alloc(4);
    size_t o_counts = alloc((size_t)NBMAX * 4);
    size_t o_offs   = alloc(((size_t)NBMAX + 1) * 4);
    size_t o_gcur   = alloc((size_t)NBMAX * 4);
    size_t o_recs   = alloc((size_t)num_edges * 8 + 64);   // +64: slow-path over-read pad
    size_t o_offs2  = alloc((((size_t)nbkt << RPB_SHIFT) + 1) * 4);
    size_t need_base = off;                                 // base incl. offs2
    size_t o_hA     = alloc((size_t)num_nodes * 64);        // fp16 dims 0-31, 64 MB
    size_t o_hB     = alloc((size_t)num_nodes * 64);        // fp16 dims 32-63, 64 MB
    size_t need_f16 = off;

    char* ws = (char*)d_ws;
    int* flag = (int*)(ws + o_flag);

    if (ws_size < need_base || nbkt > NBMAX || num_nodes > (1 << 20)) {
        detect_idx_width<<<1, 256, 0, stream>>>((const unsigned int*)eidx, flag, nullptr);
        hipMemsetAsync(d_out, 0, (size_t)out_size * sizeof(float), stream);
        long long total_threads = (long long)num_edges * 16;
        long long grid = (total_threads + 255) / 256;
        scatter_edges<<<(int)grid, 256, 0, stream>>>(
            eidx, vals, users, items, out, flag, num_users, num_edges);
        return;
    }

    int* counts  = (int*)(ws + o_counts);
    int* offs    = (int*)(ws + o_offs);
    int* gcursor = (int*)(ws + o_gcur);
    u64* recs    = (u64*)(ws + o_recs);
    int* offs2   = (int*)(ws + o_offs2);
    h4*  hA      = (h4*)(ws + o_hA);
    h4*  hB      = (h4*)(ws + o_hB);

    bool use_f16 = (ws_size >= need_f16) && ((DIM % 8) == 0);

    detect_idx_width<<<1, 256, 0, stream>>>((const unsigned int*)eidx, flag, counts);

    long long usz4 = (long long)num_users * DIM / 4;
    long long tot4 = (long long)num_nodes * DIM / 4;

    if (use_f16) {
        // fused convert + hist: one dispatch, two grid roles
        const int convB = 2048, histB = 768;
        prep<<<convB + histB, 256, 0, stream>>>((const f4v*)users, (const f4v*)items,
                                                usz4, tot4, hA, hB,
                                                eidx, flag, counts, num_edges,
                                                convB, histB);
    } else {
        hist_coarse<<<768, 256, 0, stream>>>(eidx, flag, counts, num_edges);
    }

    scan_buckets<<<1, 256, 0, stream>>>(counts, offs, gcursor,
                                        use_f16 ? nullptr : offs2, nbkt);

    int bin_grid = (num_edges + CHUNK - 1) / CHUNK;
    bin_edges<<<bin_grid, 256, 0, stream>>>(eidx, vals, flag, gcursor, recs, num_edges);

    if (use_f16) {
        sortgather_h<<<nbkt, 256, 0, stream>>>(offs, recs, (const h8*)hA,
                                               (const h8*)hB, out, num_nodes);
    } else {
        sort_bucket<<<nbkt, 256, 0, stream>>>(offs, recs, offs2);
        int gg = (num_nodes + 3) / 4;
        const float* items_m = items - (size_t)num_users * DIM;
        gather_nodes<<<gg, 256, 0, stream>>>(offs, offs2, recs, users, items_m, out,
                                             num_users, num_nodes);
    }
}

// Round 12
// 384.961 us; speedup vs baseline: 1.3774x; 1.3476x over previous
//
#include <hip/hip_runtime.h>

#define DIM 64
#define RPB 1024              // rows per coarse bucket
#define RPB_SHIFT 10
#define NBMAX 1024            // max coarse buckets supported
#define CHUNK 4096            // edges per bin_edges block
#define EPT 16                // edges per thread in bin_edges (CHUNK/256)
#define CAPT 35               // records per thread in fused sort (cap 8960 = mean+8.6 sigma)
#define SREC_CAP (CAPT * 256) // 8960 staged records (70 KB LDS)
#define NPGF 32               // nodes per 8-lane group in fused gather (RPB/32)

typedef unsigned long long u64;
typedef unsigned int u32;
typedef unsigned short u16;
typedef float f4v __attribute__((ext_vector_type(4)));
typedef _Float16 h4 __attribute__((ext_vector_type(4)));
typedef _Float16 h8 __attribute__((ext_vector_type(8)));

// ---------------- idx width detection + counts zeroing ---------------------
__global__ void detect_idx_width(const unsigned int* __restrict__ idx_words,
                                 int* __restrict__ flag,
                                 int* __restrict__ counts) {
    __shared__ unsigned int s_or[256];
    if (counts)
        for (int i = threadIdx.x; i < NBMAX; i += 256) counts[i] = 0;
    unsigned int acc = 0;
    for (int i = threadIdx.x; i < 4096; i += blockDim.x)
        acc |= idx_words[2 * i + 1];
    s_or[threadIdx.x] = acc;
    __syncthreads();
    for (int s = 128; s > 0; s >>= 1) {
        if (threadIdx.x < s) s_or[threadIdx.x] |= s_or[threadIdx.x + s];
        __syncthreads();
    }
    if (threadIdx.x == 0) *flag = (s_or[0] == 0) ? 1 : 0;
}

__device__ __forceinline__ int load_idx(const void* ei, int use64, long long i) {
    return use64 ? (int)((const long long*)ei)[i] : ((const int*)ei)[i];
}

__device__ __forceinline__ int load_idx_nt(const void* ei, int use64, long long i) {
    return use64 ? (int)__builtin_nontemporal_load(&((const long long*)ei)[i])
                 : __builtin_nontemporal_load(&((const int*)ei)[i]);
}

// block-wide exclusive scan helper over per-thread sums (wave shuffles +
// 4-entry LDS exchange; ONE barrier inside). 256-thread blocks only.
__device__ __forceinline__ u32 quad_scan_ex(u32 qs, u32* wtot, int tid, u32* total_out) {
    u32 inc = qs;
    #pragma unroll
    for (int d = 1; d < 64; d <<= 1) {
        u32 v = __shfl_up(inc, d, 64);
        if ((tid & 63) >= d) inc += v;
    }
    if ((tid & 63) == 63) wtot[tid >> 6] = inc;
    __syncthreads();
    int w = tid >> 6;
    u32 woff = 0;
    #pragma unroll
    for (int k = 0; k < 3; ++k) woff += (k < w) ? wtot[k] : 0;
    if (total_out) *total_out = wtot[0] + wtot[1] + wtot[2] + wtot[3];
    return woff + inc - qs;
}

// ---------------- fused prep: convert role + coarse-hist role --------------
__global__ __launch_bounds__(256) void prep(const f4v* __restrict__ u4,
                                            const f4v* __restrict__ i4,
                                            long long usz4, long long tot4,
                                            h4* __restrict__ dst,
                                            const void* __restrict__ ei,
                                            const int* __restrict__ flag,
                                            int* __restrict__ counts,
                                            int num_edges,
                                            int convBlocks, int histBlocks) {
    if ((int)blockIdx.x < convBlocks) {
        long long stride = (long long)convBlocks * 256;
        for (long long idx = (long long)blockIdx.x * 256 + threadIdx.x;
             idx < tot4; idx += stride) {
            const f4v* src = (idx < usz4) ? (u4 + idx) : (i4 + (idx - usz4));
            f4v f = __builtin_nontemporal_load(src);
            h4 o;
            o.x = (_Float16)f.x; o.y = (_Float16)f.y;
            o.z = (_Float16)f.z; o.w = (_Float16)f.w;
            dst[idx] = o;      // temporal: keep table LLC-resident for gather
        }
    } else {
        __shared__ int h[NBMAX];
        for (int b = threadIdx.x; b < NBMAX; b += 256) h[b] = 0;
        __syncthreads();
        int use64 = *flag;
        int hb = (int)blockIdx.x - convBlocks;
        long long tid = (long long)hb * 256 + threadIdx.x;
        long long stride = (long long)histBlocks * 256;
        long long npairs = (long long)num_edges >> 1;
        const u64* p = (const u64*)ei;
        if (use64) {
            for (long long e = tid; e < npairs; e += stride) {
                u64 a = __builtin_nontemporal_load(&p[2 * e]);
                u64 b = __builtin_nontemporal_load(&p[2 * e + 1]);
                atomicAdd(&h[(int)(u32)a >> RPB_SHIFT], 1);
                atomicAdd(&h[(int)(u32)b >> RPB_SHIFT], 1);
            }
        } else {
            for (long long e = tid; e < npairs; e += stride) {
                u64 v = __builtin_nontemporal_load(&p[e]);
                atomicAdd(&h[(int)(u32)v >> RPB_SHIFT], 1);
                atomicAdd(&h[(int)(u32)(v >> 32) >> RPB_SHIFT], 1);
            }
        }
        if (tid == 0 && (num_edges & 1)) {
            int r = load_idx(ei, use64, num_edges - 1);
            atomicAdd(&h[r >> RPB_SHIFT], 1);
        }
        __syncthreads();
        for (int b = threadIdx.x; b < NBMAX; b += 256)
            if (h[b]) atomicAdd(&counts[b], h[b]);
    }
}

// ---------------- standalone hist (f32 fallback path) ----------------------
__global__ __launch_bounds__(256) void hist_coarse(const void* __restrict__ ei,
                                                   const int* __restrict__ flag,
                                                   int* __restrict__ counts,
                                                   int num_edges) {
    __shared__ int h[NBMAX];
    for (int b = threadIdx.x; b < NBMAX; b += 256) h[b] = 0;
    __syncthreads();
    int use64 = *flag;
    long long tid = (long long)blockIdx.x * 256 + threadIdx.x;
    long long stride = (long long)gridDim.x * 256;
    long long npairs = (long long)num_edges >> 1;
    const u64* p = (const u64*)ei;
    if (use64) {
        for (long long e = tid; e < npairs; e += stride) {
            u64 a = __builtin_nontemporal_load(&p[2 * e]);
            u64 b = __builtin_nontemporal_load(&p[2 * e + 1]);
            atomicAdd(&h[(int)(u32)a >> RPB_SHIFT], 1);
            atomicAdd(&h[(int)(u32)b >> RPB_SHIFT], 1);
        }
    } else {
        for (long long e = tid; e < npairs; e += stride) {
            u64 v = __builtin_nontemporal_load(&p[e]);
            atomicAdd(&h[(int)(u32)v >> RPB_SHIFT], 1);
            atomicAdd(&h[(int)(u32)(v >> 32) >> RPB_SHIFT], 1);
        }
    }
    if (tid == 0 && (num_edges & 1)) {
        int r = load_idx(ei, use64, num_edges - 1);
        atomicAdd(&h[r >> RPB_SHIFT], 1);
    }
    __syncthreads();
    for (int b = threadIdx.x; b < NBMAX; b += 256)
        if (h[b]) atomicAdd(&counts[b], h[b]);
}

// ---------------- scan of 1024 bucket counts (1 block) ---------------------
__global__ __launch_bounds__(256) void scan_buckets(const int* __restrict__ counts,
                                                    int* __restrict__ offs,
                                                    int* __restrict__ gcursor,
                                                    int* __restrict__ offs2, int nbkt) {
    __shared__ u32 wtot[4];
    int t = threadIdx.x;
    int4 h = ((const int4*)counts)[t];
    u32 qs = (u32)(h.x + h.y + h.z + h.w);
    u32 total;
    u32 ex = quad_scan_ex(qs, wtot, t, &total);
    int o0 = (int)ex, o1 = o0 + h.x, o2 = o1 + h.y, o3 = o2 + h.z;
    offs[4*t] = o0; offs[4*t+1] = o1; offs[4*t+2] = o2; offs[4*t+3] = o3;
    gcursor[4*t] = o0; gcursor[4*t+1] = o1; gcursor[4*t+2] = o2; gcursor[4*t+3] = o3;
    if (t == 255) {
        offs[NBMAX] = (int)total;
        if (offs2) offs2[(long long)nbkt << RPB_SHIFT] = (int)total; // f32 path
    }
}

// ---------------- pass 3: LDS-staged coarse binning (R7-proven) ------------
// record: [w:32][rowlocal:10][col:20]
__global__ __launch_bounds__(256) void bin_edges(const void* __restrict__ ei,
                                                 const float* __restrict__ vals,
                                                 const int* __restrict__ flag,
                                                 int* __restrict__ gcursor,
                                                 u64* __restrict__ recs,
                                                 int num_edges) {
    __shared__ u32 hist[NBMAX];     // counts, then running cursor
    __shared__ u32 scanL[NBMAX];
    __shared__ u32 gbase[NBMAX];
    __shared__ u32 wtot[4];
    __shared__ u64 payload[CHUNK];
    __shared__ u16 bidv[CHUNK];

    int tid = threadIdx.x;
    long long base = (long long)blockIdx.x * CHUNK;
    int n = (int)min((long long)CHUNK, (long long)num_edges - base);
    int use64 = *flag;

    for (int b = tid; b < NBMAX; b += 256) hist[b] = 0;
    __syncthreads();

    int rows_[EPT]; int cols_[EPT]; float ws_[EPT];
    #pragma unroll
    for (int i = 0; i < EPT; ++i) {
        int j = tid + i * 256;
        rows_[i] = -1;
        if (j < n) {
            long long e = base + j;
            rows_[i] = load_idx_nt(ei, use64, e);
            cols_[i] = load_idx_nt(ei, use64, (long long)num_edges + e);
            ws_[i]   = __builtin_nontemporal_load(&vals[e]);
            atomicAdd(&hist[rows_[i] >> RPB_SHIFT], 1u);
        }
    }
    __syncthreads();

    // exclusive scan of 1024 counts (wave-shuffle, 1 barrier)
    u32 h0 = hist[4*tid], h1 = hist[4*tid+1], h2 = hist[4*tid+2], h3 = hist[4*tid+3];
    u32 ex = quad_scan_ex(h0 + h1 + h2 + h3, wtot, tid, nullptr);
    scanL[4*tid]   = ex;
    scanL[4*tid+1] = ex + h0;
    scanL[4*tid+2] = ex + h0 + h1;
    scanL[4*tid+3] = ex + h0 + h1 + h2;
    __syncthreads();

    // reserve global space per bucket
    for (int b = tid; b < NBMAX; b += 256) {
        u32 c = hist[b];
        gbase[b] = c ? (u32)atomicAdd(&gcursor[b], (int)c) : 0u;
    }
    __syncthreads();
    for (int b = tid; b < NBMAX; b += 256) hist[b] = scanL[b];
    __syncthreads();

    // scatter records into LDS ordered by bucket
    #pragma unroll
    for (int i = 0; i < EPT; ++i) {
        if (rows_[i] >= 0) {
            int b = rows_[i] >> RPB_SHIFT;
            u32 pos = atomicAdd(&hist[b], 1u);
            u32 rl = (u32)(rows_[i] & (RPB - 1));
            payload[pos] = ((u64)__float_as_uint(ws_[i]) << 32) | (rl << 20) | (u32)cols_[i];
            bidv[pos] = (u16)b;
        }
    }
    __syncthreads();

    // flush: consecutive LDS slots -> consecutive global slots per bucket run
    for (int j = tid; j < n; j += 256) {
        u64 rec = payload[j];
        int b = bidv[j];
        recs[gbase[b] + (u32)j - scanL[b]] = rec;
    }
}

// ---------------- fp16: FUSED per-bucket sort + gather ---------------------
#define ACC8(P0, P1, W, V) \
    P0.x += W * (float)V[0]; P0.y += W * (float)V[1]; \
    P0.z += W * (float)V[2]; P0.w += W * (float)V[3]; \
    P1.x += W * (float)V[4]; P1.y += W * (float)V[5]; \
    P1.z += W * (float)V[6]; P1.w += W * (float)V[7];

__global__ __launch_bounds__(256, 2) void sortgather_h(const int* __restrict__ offs,
                                                       const u64* __restrict__ recs,
                                                       const h8* __restrict__ hemb8,
                                                       float* __restrict__ out,
                                                       int num_nodes) {
    __shared__ u64 s_recs[SREC_CAP];     // 70 KB
    __shared__ u32 node_beg[RPB + 1];    // 4 KB
    __shared__ u32 cursor[RPB];          // 4 KB (bins, then scatter cursor)
    __shared__ u32 wtot[4];

    int b  = blockIdx.x;
    int t  = threadIdx.x;
    int l8 = t & 7;
    int g  = t >> 3;                     // group id 0..31
    int beg = offs[b], end = offs[b + 1];
    int cnt = end - beg;
    int row0 = b << RPB_SHIFT;

    if (cnt <= SREC_CAP) {
        // ---- sort phase: registers -> exact LDS positions ----
        u64 r_[CAPT];
        #pragma unroll
        for (int k = 0; k < CAPT; ++k) {
            int j = t + k * 256;
            r_[k] = (j < cnt) ? __builtin_nontemporal_load(&recs[beg + j]) : 0ull;
        }
        for (int i = t; i < RPB; i += 256) cursor[i] = 0;
        __syncthreads();
        #pragma unroll
        for (int k = 0; k < CAPT; ++k) {
            int j = t + k * 256;
            if (j < cnt) atomicAdd(&cursor[(u32)(r_[k] >> 20) & (RPB - 1)], 1u);
        }
        __syncthreads();
        u32 c0[4]; u32 s = 0;
        #pragma unroll
        for (int i = 0; i < 4; ++i) { c0[i] = cursor[t * 4 + i]; s += c0[i]; }
        u32 ex = quad_scan_ex(s, wtot, t, nullptr);
        #pragma unroll
        for (int i = 0; i < 4; ++i) {
            node_beg[t * 4 + i] = ex;
            cursor[t * 4 + i] = ex;
            ex += c0[i];
        }
        if (t == 0) node_beg[RPB] = (u32)cnt;
        __syncthreads();
        #pragma unroll
        for (int k = 0; k < CAPT; ++k) {
            int j = t + k * 256;
            if (j < cnt) {
                u32 rl = (u32)(r_[k] >> 20) & (RPB - 1);
                u32 pos = atomicAdd(&cursor[rl], 1u);
                s_recs[pos] = r_[k];
            }
        }
        __syncthreads();

        // ---- gather phase: group g owns nodes [g*32, g*32+32) ----
        for (int nn = 0; nn < NPGF; ++nn) {
            int ln = g * NPGF + nn;
            int node = row0 + ln;
            if (node >= num_nodes) break;
            int nb = (int)node_beg[ln];
            int ne = (int)node_beg[ln + 1];

            float4 p0 = make_float4(0.f,0.f,0.f,0.f), p1 = make_float4(0.f,0.f,0.f,0.f);
            float4 q0 = make_float4(0.f,0.f,0.f,0.f), q1 = make_float4(0.f,0.f,0.f,0.f);

            int i = nb;
            for (; i + 8 <= ne; i += 8) {
                u64 s0 = s_recs[i];     u64 s1 = s_recs[i + 1];
                u64 s2 = s_recs[i + 2]; u64 s3 = s_recs[i + 3];
                u64 s4 = s_recs[i + 4]; u64 s5 = s_recs[i + 5];
                u64 s6 = s_recs[i + 6]; u64 s7 = s_recs[i + 7];
                h8 v0 = hemb8[(((u32)s0 & 0xFFFFFu) << 3) + l8];
                h8 v1 = hemb8[(((u32)s1 & 0xFFFFFu) << 3) + l8];
                h8 v2 = hemb8[(((u32)s2 & 0xFFFFFu) << 3) + l8];
                h8 v3 = hemb8[(((u32)s3 & 0xFFFFFu) << 3) + l8];
                h8 v4 = hemb8[(((u32)s4 & 0xFFFFFu) << 3) + l8];
                h8 v5 = hemb8[(((u32)s5 & 0xFFFFFu) << 3) + l8];
                h8 v6 = hemb8[(((u32)s6 & 0xFFFFFu) << 3) + l8];
                h8 v7 = hemb8[(((u32)s7 & 0xFFFFFu) << 3) + l8];
                float w0 = __uint_as_float((u32)(s0 >> 32));
                float w1 = __uint_as_float((u32)(s1 >> 32));
                float w2 = __uint_as_float((u32)(s2 >> 32));
                float w3 = __uint_as_float((u32)(s3 >> 32));
                float w4 = __uint_as_float((u32)(s4 >> 32));
                float w5 = __uint_as_float((u32)(s5 >> 32));
                float w6 = __uint_as_float((u32)(s6 >> 32));
                float w7 = __uint_as_float((u32)(s7 >> 32));
                ACC8(p0, p1, w0, v0); ACC8(q0, q1, w1, v1);
                ACC8(p0, p1, w2, v2); ACC8(q0, q1, w3, v3);
                ACC8(p0, p1, w4, v4); ACC8(q0, q1, w5, v5);
                ACC8(p0, p1, w6, v6); ACC8(q0, q1, w7, v7);
            }
            if (i < ne) {
                int last = ne - 1;
                int e1 = min(i + 1, last), e2 = min(i + 2, last);
                int e3 = min(i + 3, last), e4 = min(i + 4, last);
                int e5 = min(i + 5, last), e6 = min(i + 6, last);
                u64 s0 = s_recs[i];  u64 s1 = s_recs[e1];
                u64 s2 = s_recs[e2]; u64 s3 = s_recs[e3];
                u64 s4 = s_recs[e4]; u64 s5 = s_recs[e5];
                u64 s6 = s_recs[e6];
                h8 v0 = hemb8[(((u32)s0 & 0xFFFFFu) << 3) + l8];
                h8 v1 = hemb8[(((u32)s1 & 0xFFFFFu) << 3) + l8];
                h8 v2 = hemb8[(((u32)s2 & 0xFFFFFu) << 3) + l8];
                h8 v3 = hemb8[(((u32)s3 & 0xFFFFFu) << 3) + l8];
                h8 v4 = hemb8[(((u32)s4 & 0xFFFFFu) << 3) + l8];
                h8 v5 = hemb8[(((u32)s5 & 0xFFFFFu) << 3) + l8];
                h8 v6 = hemb8[(((u32)s6 & 0xFFFFFu) << 3) + l8];
                float w0 = __uint_as_float((u32)(s0 >> 32));
                float w1 = (i + 1 < ne) ? __uint_as_float((u32)(s1 >> 32)) : 0.f;
                float w2 = (i + 2 < ne) ? __uint_as_float((u32)(s2 >> 32)) : 0.f;
                float w3 = (i + 3 < ne) ? __uint_as_float((u32)(s3 >> 32)) : 0.f;
                float w4 = (i + 4 < ne) ? __uint_as_float((u32)(s4 >> 32)) : 0.f;
                float w5 = (i + 5 < ne) ? __uint_as_float((u32)(s5 >> 32)) : 0.f;
                float w6 = (i + 6 < ne) ? __uint_as_float((u32)(s6 >> 32)) : 0.f;
                ACC8(p0, p1, w0, v0); ACC8(q0, q1, w1, v1);
                ACC8(p0, p1, w2, v2); ACC8(q0, q1, w3, v3);
                ACC8(p0, p1, w4, v4); ACC8(q0, q1, w5, v5);
                ACC8(p0, p1, w6, v6);
            }

            p0.x += q0.x; p0.y += q0.y; p0.z += q0.z; p0.w += q0.w;
            p1.x += q1.x; p1.y += q1.y; p1.z += q1.z; p1.w += q1.w;
            f4v o0; o0.x = p0.x; o0.y = p0.y; o0.z = p0.z; o0.w = p0.w;
            f4v o1; o1.x = p1.x; o1.y = p1.y; o1.z = p1.z; o1.w = p1.w;
            f4v* dst = (f4v*)out + ((long long)node << 4) + (l8 << 1);
            __builtin_nontemporal_store(o0, dst);
            __builtin_nontemporal_store(o1, dst + 1);
        }
    } else {
        // overflow slow path (cnt > SREC_CAP): per node, scan the whole
        // coarse bucket from global with rowlocal + bound masking.
        for (int nn = 0; nn < NPGF; ++nn) {
            int ln = g * NPGF + nn;
            int node = row0 + ln;
            if (node >= num_nodes) break;
            u32 rl = (u32)ln;

            float4 p0 = make_float4(0.f,0.f,0.f,0.f), p1 = make_float4(0.f,0.f,0.f,0.f);
            float4 q0 = make_float4(0.f,0.f,0.f,0.f), q1 = make_float4(0.f,0.f,0.f,0.f);
            int last = end - 1;
            u32 rm = RPB - 1;
            for (int i = beg; i < end; i += 4) {
                int e1 = min(i + 1, last), e2 = min(i + 2, last), e3 = min(i + 3, last);
                u64 s0 = recs[i];  u64 s1 = recs[e1];
                u64 s2 = recs[e2]; u64 s3 = recs[e3];
                h8 v0 = hemb8[(((u32)s0 & 0xFFFFFu) << 3) + l8];
                h8 v1 = hemb8[(((u32)s1 & 0xFFFFFu) << 3) + l8];
                h8 v2 = hemb8[(((u32)s2 & 0xFFFFFu) << 3) + l8];
                h8 v3 = hemb8[(((u32)s3 & 0xFFFFFu) << 3) + l8];
                float w0 = ((((u32)(s0 >> 20)) & rm) == rl)
                           ? __uint_as_float((u32)(s0 >> 32)) : 0.f;
                float w1 = (((((u32)(s1 >> 20)) & rm) == rl) & (i + 1 < end))
                           ? __uint_as_float((u32)(s1 >> 32)) : 0.f;
                float w2 = (((((u32)(s2 >> 20)) & rm) == rl) & (i + 2 < end))
                           ? __uint_as_float((u32)(s2 >> 32)) : 0.f;
                float w3 = (((((u32)(s3 >> 20)) & rm) == rl) & (i + 3 < end))
                           ? __uint_as_float((u32)(s3 >> 32)) : 0.f;
                ACC8(p0, p1, w0, v0); ACC8(q0, q1, w1, v1);
                ACC8(p0, p1, w2, v2); ACC8(q0, q1, w3, v3);
            }
            p0.x += q0.x; p0.y += q0.y; p0.z += q0.z; p0.w += q0.w;
            p1.x += q1.x; p1.y += q1.y; p1.z += q1.z; p1.w += q1.w;
            f4v o0; o0.x = p0.x; o0.y = p0.y; o0.z = p0.z; o0.w = p0.w;
            f4v o1; o1.x = p1.x; o1.y = p1.y; o1.z = p1.z; o1.w = p1.w;
            f4v* dst = (f4v*)out + ((long long)node << 4) + (l8 << 1);
            __builtin_nontemporal_store(o0, dst);
            __builtin_nontemporal_store(o1, dst + 1);
        }
    }
}

// ---------------- f32 fallback path: split sort + gather -------------------
__global__ __launch_bounds__(256, 2) void sort_bucket(const int* __restrict__ offs,
                                                      u64* __restrict__ recs,
                                                      int* __restrict__ offs2) {
    __shared__ u32 bins[RPB];    // 4 KB
    __shared__ u32 wtot[4];
    int b = blockIdx.x;
    int t = threadIdx.x;
    int beg = offs[b], end = offs[b + 1];
    int cnt = end - beg;
    int row0 = b << RPB_SHIFT;

    if (cnt > CAPT * 256) {
        for (int i = t; i < RPB; i += 256) offs2[row0 + i] = -(b + 1);
        return;
    }

    u64 r_[CAPT];
    #pragma unroll
    for (int k = 0; k < CAPT; ++k) {
        int j = t + k * 256;
        r_[k] = (j < cnt) ? recs[beg + j] : 0ull;
    }
    for (int i = t; i < RPB; i += 256) bins[i] = 0;
    __syncthreads();

    #pragma unroll
    for (int k = 0; k < CAPT; ++k) {
        int j = t + k * 256;
        if (j < cnt) atomicAdd(&bins[(u32)(r_[k] >> 20) & (RPB - 1)], 1u);
    }
    __syncthreads();

    u32 c0[4]; u32 s = 0;
    #pragma unroll
    for (int i = 0; i < 4; ++i) { c0[i] = bins[t * 4 + i]; s += c0[i]; }
    u32 ex = quad_scan_ex(s, wtot, t, nullptr);
    #pragma unroll
    for (int i = 0; i < 4; ++i) {
        bins[t * 4 + i] = ex;
        offs2[row0 + t * 4 + i] = beg + (int)ex;
        ex += c0[i];
    }
    __syncthreads();

    #pragma unroll
    for (int k = 0; k < CAPT; ++k) {
        int j = t + k * 256;
        if (j < cnt) {
            u32 rl = (u32)(r_[k] >> 20) & (RPB - 1);
            u32 pos = atomicAdd(&bins[rl], 1u);
            recs[beg + pos] = r_[k];
        }
    }
}

__device__ __forceinline__ void gstep(u64 s, u32 rl,
                                      const float* __restrict__ users,
                                      const float* __restrict__ items_m,
                                      int num_users, int l16, float4& a) {
    int c = (int)(s & 0xFFFFFu);
    float w = __uint_as_float((u32)(s >> 32));
    w = (((u32)(s >> 20) & (RPB - 1)) == rl) ? w : 0.f;
    const float* p = ((c < num_users) ? users : items_m) + ((u32)c << 6);
    float4 m = reinterpret_cast<const float4*>(p)[l16];
    a.x += w * m.x; a.y += w * m.y; a.z += w * m.z; a.w += w * m.w;
}

__global__ __launch_bounds__(256) void gather_nodes(const int* __restrict__ offs,
                                                    const int* __restrict__ offs2,
                                                    const u64* __restrict__ recs,
                                                    const float* __restrict__ users,
                                                    const float* __restrict__ items_m,
                                                    float* __restrict__ out,
                                                    int num_users, int num_nodes) {
    int node = blockIdx.x * (blockDim.x >> 6) + (threadIdx.x >> 6);
    int lane = threadIdx.x & 63;
    if (node >= num_nodes) return;
    int q   = lane >> 4;
    int l16 = lane & 15;

    int beg = offs2[node];
    int end = offs2[node + 1];
    if (beg < 0) { int b = node >> RPB_SHIFT; beg = offs[b]; end = offs[b + 1]; }
    else if (end < 0) { end = offs[(node >> RPB_SHIFT) + 1]; }
    u32 rl = (u32)(node & (RPB - 1));

    float4 a0 = make_float4(0.f, 0.f, 0.f, 0.f);
    float4 a1 = make_float4(0.f, 0.f, 0.f, 0.f);

    int i = beg + q;
    for (; i + 4 < end; i += 8) {
        u64 s0 = recs[i];
        u64 s1 = recs[i + 4];
        gstep(s0, rl, users, items_m, num_users, l16, a0);
        gstep(s1, rl, users, items_m, num_users, l16, a1);
    }
    if (i < end) {
        u64 s0 = recs[i];
        gstep(s0, rl, users, items_m, num_users, l16, a0);
    }
    a0.x += a1.x; a0.y += a1.y; a0.z += a1.z; a0.w += a1.w;

    for (int msk = 16; msk <= 32; msk <<= 1) {
        a0.x += __shfl_xor(a0.x, msk, 64);
        a0.y += __shfl_xor(a0.y, msk, 64);
        a0.z += __shfl_xor(a0.z, msk, 64);
        a0.w += __shfl_xor(a0.w, msk, 64);
    }
    if (q == 0)
        reinterpret_cast<float4*>(out)[(long long)node * 16 + l16] = a0;
}

// ---------------- fallback: R1 atomic scatter ------------------------------
__global__ __launch_bounds__(256) void scatter_edges(const void* __restrict__ edge_index,
                                                     const float* __restrict__ vals,
                                                     const float* __restrict__ users,
                                                     const float* __restrict__ items,
                                                     float* __restrict__ out,
                                                     const int* __restrict__ idx64_flag,
                                                     int num_users, int num_edges) {
    long long gid = (long long)blockIdx.x * blockDim.x + threadIdx.x;
    long long e = gid >> 4;
    int lane = (int)(gid & 15);
    if (e >= num_edges) return;
    int use64 = *idx64_flag;
    int r = load_idx(edge_index, use64, e);
    int c = load_idx(edge_index, use64, (long long)num_edges + e);
    float w = vals[e];
    const float* src = (c < num_users)
        ? (users + (long long)c * DIM)
        : (items + (long long)(c - num_users) * DIM);
    float4 m = reinterpret_cast<const float4*>(src)[lane];
    float* dst = out + (long long)r * DIM + lane * 4;
    unsafeAtomicAdd(dst + 0, m.x * w);
    unsafeAtomicAdd(dst + 1, m.y * w);
    unsafeAtomicAdd(dst + 2, m.z * w);
    unsafeAtomicAdd(dst + 3, m.w * w);
}

extern "C" void kernel_launch(void* const* d_in, const int* in_sizes, int n_in,
                              void* d_out, int out_size, void* d_ws, size_t ws_size,
                              hipStream_t stream) {
    const float* users = (const float*)d_in[0];
    const float* items = (const float*)d_in[1];
    const void*  eidx  = d_in[2];
    const float* vals  = (const float*)d_in[3];
    float* out = (float*)d_out;

    int num_users = in_sizes[0] / DIM;               // 600000
    int num_items = in_sizes[1] / DIM;               // 400000
    int num_nodes = num_users + num_items;           // 1000000
    int num_edges = in_sizes[3];                     // 8000000
    int nbkt = (num_nodes + RPB - 1) >> RPB_SHIFT;   // 977

    // workspace layout: base | offs2 (f32 path only) | hemb (f16 path)
    size_t off = 0;
    auto alloc = [&](size_t bytes) { size_t p = off; off = (off + bytes + 255) & ~(size_t)255; return p; };
    size_t o_flag   = alloc(4);
    size_t o_counts = alloc((size_t)NBMAX * 4);
    size_t o_offs   = alloc(((size_t)NBMAX + 1) * 4);
    size_t o_gcur   = alloc((size_t)NBMAX * 4);
    size_t o_recs   = alloc((size_t)num_edges * 8 + 64);   // +64: slow-path over-read pad
    size_t o_offs2  = alloc((((size_t)nbkt << RPB_SHIFT) + 1) * 4);
    size_t need_base = off;                                 // base incl. offs2
    size_t o_hemb   = alloc((size_t)num_nodes * DIM * 2);   // fp16 table, 128 MB
    size_t need_f16 = off;

    char* ws = (char*)d_ws;
    int* flag = (int*)(ws + o_flag);

    if (ws_size < need_base || nbkt > NBMAX || num_nodes > (1 << 20)) {
        detect_idx_width<<<1, 256, 0, stream>>>((const unsigned int*)eidx, flag, nullptr);
        hipMemsetAsync(d_out, 0, (size_t)out_size * sizeof(float), stream);
        long long total_threads = (long long)num_edges * 16;
        long long grid = (total_threads + 255) / 256;
        scatter_edges<<<(int)grid, 256, 0, stream>>>(
            eidx, vals, users, items, out, flag, num_users, num_edges);
        return;
    }

    int* counts  = (int*)(ws + o_counts);
    int* offs    = (int*)(ws + o_offs);
    int* gcursor = (int*)(ws + o_gcur);
    u64* recs    = (u64*)(ws + o_recs);
    int* offs2   = (int*)(ws + o_offs2);
    h4*  hemb4   = (h4*)(ws + o_hemb);

    bool use_f16 = (ws_size >= need_f16) && ((DIM % 8) == 0);

    detect_idx_width<<<1, 256, 0, stream>>>((const unsigned int*)eidx, flag, counts);

    long long usz4 = (long long)num_users * DIM / 4;
    long long tot4 = (long long)num_nodes * DIM / 4;

    if (use_f16) {
        // fused convert + hist: one dispatch, two grid roles
        const int convB = 2048, histB = 768;
        prep<<<convB + histB, 256, 0, stream>>>((const f4v*)users, (const f4v*)items,
                                                usz4, tot4, hemb4,
                                                eidx, flag, counts, num_edges,
                                                convB, histB);
    } else {
        hist_coarse<<<768, 256, 0, stream>>>(eidx, flag, counts, num_edges);
    }

    scan_buckets<<<1, 256, 0, stream>>>(counts, offs, gcursor,
                                        use_f16 ? nullptr : offs2, nbkt);

    int bin_grid = (num_edges + CHUNK - 1) / CHUNK;
    bin_edges<<<bin_grid, 256, 0, stream>>>(eidx, vals, flag, gcursor, recs, num_edges);

    if (use_f16) {
        sortgather_h<<<nbkt, 256, 0, stream>>>(offs, recs, (const h8*)hemb4,
                                               out, num_nodes);
    } else {
        sort_bucket<<<nbkt, 256, 0, stream>>>(offs, recs, offs2);
        int gg = (num_nodes + 3) / 4;
        const float* items_m = items - (size_t)num_users * DIM;
        gather_nodes<<<gg, 256, 0, stream>>>(offs, offs2, recs, users, items_m, out,
                                             num_users, num_nodes);
    }
}